// Round 3
// baseline (966.205 us; speedup 1.0000x reference)
//
#include <hip/hip_runtime.h>
#include <hip/hip_bf16.h>

typedef __bf16 bf16;
typedef __attribute__((ext_vector_type(4))) float f32x4;
typedef __attribute__((ext_vector_type(8))) bf16 bf16x8;

#define NCAMS 6
#define NQ 6400
#define CH 256
#define NH 8
#define NL 3
#define NP 8
#define S_TOT 14784   // 64*176 + 32*88 + 16*44

// ---------------------------------------------------------------- K0: zero the slots accumulator
__global__ __launch_bounds__(256) void k_zero(float* __restrict__ slots)
{
    int idx = blockIdx.x * 256 + threadIdx.x;      // 1600*256 threads * 4 f32 = 1,638,400
    reinterpret_cast<f32x4*>(slots)[idx] = (f32x4){0.f, 0.f, 0.f, 0.f};
}

// ---------------------------------------------------------------- K1: projection
__global__ __launch_bounds__(256) void k_proj(
    const float* __restrict__ means, const float* __restrict__ cam2ego,
    const float* __restrict__ intrins, const float* __restrict__ post_rots,
    const float* __restrict__ post_trans, const int* __restrict__ img_h,
    const int* __restrict__ img_w, float* __restrict__ coor, float* __restrict__ maskf)
{
    int idx = blockIdx.x * 256 + threadIdx.x;
    if (idx >= NCAMS * NQ) return;
    int cam = idx / NQ, n = idx % NQ;
    float mx = means[n*3+0], my = means[n*3+1], mz = means[n*3+2];
    const float* M = cam2ego + cam*16;
    float R[3][3], t[3];
    #pragma unroll
    for (int r = 0; r < 3; r++) {
        #pragma unroll
        for (int c = 0; c < 3; c++) R[r][c] = M[r*4+c];
        t[r] = M[r*4+3];
    }
    // rigid inverse: p_cam = R^T (m - t)
    float dx = mx - t[0], dy = my - t[1], dz = mz - t[2];
    float xc = R[0][0]*dx + R[1][0]*dy + R[2][0]*dz;
    float yc = R[0][1]*dx + R[1][1]*dy + R[2][1]*dz;
    float zc = R[0][2]*dx + R[1][2]*dy + R[2][2]*dz;
    const float* K = intrins + cam*9;
    float ix = K[0]*xc + K[1]*yc + K[2]*zc;
    float iy = K[3]*xc + K[4]*yc + K[5]*zc;
    float iz = K[6]*xc + K[7]*yc + K[8]*zc;
    float px = ix / (iz + 1e-4f), py = iy / (iz + 1e-4f), pz = iz;
    const float* P = post_rots + cam*9;
    const float* T = post_trans + cam*3;
    float vx = P[0]*px + P[1]*py + P[2]*pz + T[0];
    float vy = P[3]*px + P[4]*py + P[5]*pz + T[1];
    float vz = P[6]*px + P[7]*py + P[8]*pz + T[2];
    float cx = vx / (float)img_w[0];
    float cy = vy / (float)img_h[0];
    bool ok = (vz > 0.01f) && (cx > 0.f) && (cx < 1.f) && (cy > 0.f) && (cy < 1.f);
    coor[idx*2+0] = cx;
    coor[idx*2+1] = cy;
    maskf[idx] = ok ? 1.f : 0.f;
}

// ---------------------------------------------------------------- K2: offsets + attn (+softmax)
__global__ __launch_bounds__(256) void k_offattn(
    const float* __restrict__ feature, const float* __restrict__ W_off,
    const float* __restrict__ b_off, const float* __restrict__ W_attn,
    const float* __restrict__ b_attn, float* __restrict__ offs, bf16* __restrict__ attn_out)
{
    __shared__ float ft[256*8];    // [k][q]
    __shared__ float lg[8*192];    // attn logits [q][a]
    int t = threadIdx.x;
    int n0 = blockIdx.x * 8;
    #pragma unroll
    for (int q = 0; q < 8; q++) ft[t*8+q] = feature[(size_t)(n0+q)*CH + t];
    __syncthreads();

    float a0[8] = {}, a1[8] = {}, a2[8] = {};
    for (int k = 0; k < 256; k++) {
        float w0 = W_off[k*384 + t];
        float w1 = (t < 128) ? W_off[k*384 + 256 + t] : W_attn[k*192 + (t-128)];
        float w2 = (t < 64) ? W_attn[k*192 + 128 + t] : 0.f;
        const float* fk = &ft[k*8];
        #pragma unroll
        for (int q = 0; q < 8; q++) {
            float f = fk[q];
            a0[q] += f*w0; a1[q] += f*w1; a2[q] += f*w2;
        }
    }
    float b0 = b_off[t];
    #pragma unroll
    for (int q = 0; q < 8; q++) offs[(size_t)(n0+q)*384 + t] = a0[q] + b0;
    if (t < 128) {
        float b1 = b_off[256 + t];
        #pragma unroll
        for (int q = 0; q < 8; q++) offs[(size_t)(n0+q)*384 + 256 + t] = a1[q] + b1;
    } else {
        float b1 = b_attn[t-128];
        #pragma unroll
        for (int q = 0; q < 8; q++) lg[q*192 + (t-128)] = a1[q] + b1;
    }
    if (t < 64) {
        float b2 = b_attn[128 + t];
        #pragma unroll
        for (int q = 0; q < 8; q++) lg[q*192 + 128 + t] = a2[q] + b2;
    }
    __syncthreads();
    if (t < 64) {
        int q = t >> 3, h = t & 7;
        const float* L = &lg[q*192 + h*24];
        float m = -1e30f;
        #pragma unroll
        for (int j = 0; j < 24; j++) m = fmaxf(m, L[j]);
        float e[24]; float s = 0.f;
        #pragma unroll
        for (int j = 0; j < 24; j++) { e[j] = __expf(L[j] - m); s += e[j]; }
        float inv = 1.f / s;
        #pragma unroll
        for (int j = 0; j < 24; j++) attn_out[(size_t)(n0+q)*192 + h*24 + j] = (bf16)(e[j]*inv);
    }
}

// ---------------------------------------------------------------- K3a: pack W_val into B-fragment order (bf16)
__global__ __launch_bounds__(256) void k_pack(const float* __restrict__ W_val, bf16* __restrict__ Wvp)
{
    int flat = blockIdx.x * 256 + threadIdx.x;   // 0..8191 = (kc*16+nf)*64 + lane
    int kc = flat >> 10;
    int rem = flat & 1023;
    int nf = rem >> 6;
    int lane = rem & 63;
    int q = lane >> 4;
    int col = nf*16 + (lane & 15);
    bf16x8 v;
    #pragma unroll
    for (int j = 0; j < 8; j++) v[j] = (bf16)W_val[(size_t)(kc*32 + q*8 + j)*256 + col];
    *reinterpret_cast<bf16x8*>(Wvp + (size_t)flat*8) = v;
}

// ---------------------------------------------------------------- K3: value projection GEMM (MFMA bf16)
__global__ __launch_bounds__(256) void k_valproj(
    const float* __restrict__ f0, const float* __restrict__ f1, const float* __restrict__ f2,
    const float* __restrict__ cams_embeds, const float* __restrict__ level_embeds,
    const bf16* __restrict__ Wvp, const float* __restrict__ b_val, bf16* __restrict__ value)
{
    __shared__ alignas(16) bf16 A[64][48];   // [m][k], padded row 48
    int bi = blockIdx.x;
    int cam = bi / 231, mb = bi % 231;
    int lvl, local0, HW;
    const float* fp;
    if (mb < 176)      { lvl = 0; local0 = mb*64;        fp = f0; HW = 11264; }
    else if (mb < 220) { lvl = 1; local0 = (mb-176)*64;  fp = f1; HW = 2816;  }
    else               { lvl = 2; local0 = (mb-220)*64;  fp = f2; HW = 704;   }
    int pos0 = (lvl == 0 ? 0 : (lvl == 1 ? 11264 : 14080)) + local0;
    const float* featbase = fp + (size_t)cam*CH*HW + local0;

    int t = threadIdx.x;
    int lane = t & 63, w = t >> 6;
    int kk = t >> 3;            // 0..31 (channel within chunk)
    int m8 = (t & 7) * 8;       // m start
    int q = lane >> 4, r16 = lane & 15;

    f32x4 acc[4][4];
    #pragma unroll
    for (int i = 0; i < 4; i++)
        #pragma unroll
        for (int j = 0; j < 4; j++) acc[i][j] = (f32x4){0.f,0.f,0.f,0.f};

    for (int kc = 0; kc < 8; kc++) {
        __syncthreads();
        int kg = kc*32 + kk;
        float e = cams_embeds[cam*CH + kg] + level_embeds[lvl*CH + kg];
        f32x4 v0 = *reinterpret_cast<const f32x4*>(featbase + (size_t)kg*HW + m8);
        f32x4 v1 = *reinterpret_cast<const f32x4*>(featbase + (size_t)kg*HW + m8 + 4);
        #pragma unroll
        for (int i = 0; i < 4; i++) A[m8+i][kk]   = (bf16)(v0[i] + e);
        #pragma unroll
        for (int i = 0; i < 4; i++) A[m8+4+i][kk] = (bf16)(v1[i] + e);
        __syncthreads();

        bf16x8 bfr[4];
        #pragma unroll
        for (int nf = 0; nf < 4; nf++) {
            int nfg = w*4 + nf;
            bfr[nf] = *reinterpret_cast<const bf16x8*>(Wvp + ((size_t)(kc*16 + nfg)*64 + lane)*8);
        }
        #pragma unroll
        for (int mf = 0; mf < 4; mf++) {
            bf16x8 afr = *reinterpret_cast<const bf16x8*>(&A[mf*16 + r16][q*8]);
            #pragma unroll
            for (int nf = 0; nf < 4; nf++)
                acc[mf][nf] = __builtin_amdgcn_mfma_f32_16x16x32_bf16(afr, bfr[nf], acc[mf][nf], 0, 0, 0);
        }
    }
    // epilogue: D[row=(lane>>4)*4+r][col=lane&15]
    #pragma unroll
    for (int mf = 0; mf < 4; mf++) {
        #pragma unroll
        for (int nf = 0; nf < 4; nf++) {
            int c = w*64 + nf*16 + r16;
            float bv = b_val[c];
            #pragma unroll
            for (int r = 0; r < 4; r++) {
                int srow = pos0 + mf*16 + q*4 + r;
                value[((size_t)cam*S_TOT + srow)*CH + c] = (bf16)(acc[mf][nf][r] + bv);
            }
        }
    }
}

// ---------------------------------------------------------------- K4: MSDA gather (+mask, atomic cam-reduce)
__global__ __launch_bounds__(256) void k_msda(
    const float* __restrict__ coor, const float* __restrict__ offs,
    const bf16* __restrict__ attn, const bf16* __restrict__ value,
    const float* __restrict__ maskf, float* __restrict__ slots)
{
    int wid = blockIdx.x * 4 + (threadIdx.x >> 6);
    int lane = threadIdx.x & 63;
    int cam = wid % NCAMS;
    int n = wid / NCAMS;
    float m = maskf[cam*NQ + n];
    if (m == 0.f) return;                     // wave-uniform: masked-out cam contributes nothing
    int h2 = lane >> 5, d = lane & 31;
    float cx = coor[(cam*NQ + n)*2 + 0];
    float cy = coor[(cam*NQ + n)*2 + 1];
    const bf16* vbase = value + (size_t)cam * S_TOT * CH;

    for (int ho = 0; ho < 4; ho++) {
        int h = ho*2 + h2;
        float acc = 0.f;
        #pragma unroll
        for (int lvl = 0; lvl < 3; lvl++) {
            constexpr int LW[3] = {176, 88, 44};
            constexpr int LH[3] = {64, 32, 16};
            constexpr int LS[3] = {0, 11264, 14080};
            const int wi = LW[lvl], hi = LH[lvl], base = LS[lvl];
            const float wf = (float)wi, hf = (float)hi;
            for (int p = 0; p < NP; p++) {
                float aw = (float)attn[(size_t)n*192 + h*24 + lvl*8 + p];
                int oidx = ((h*3 + lvl)*8 + p)*2;
                float ox = offs[(size_t)n*384 + oidx];
                float oy = offs[(size_t)n*384 + oidx + 1];
                float x = cx*wf + ox - 0.5f;
                float y = cy*hf + oy - 0.5f;
                float xf = floorf(x), yf = floorf(y);
                float tx = x - xf, ty = y - yf;
                int x0 = (int)xf, y0 = (int)yf;
                float w00 = (1.f-tx)*(1.f-ty)*aw, w10 = tx*(1.f-ty)*aw;
                float w01 = (1.f-tx)*ty*aw,       w11 = tx*ty*aw;
                bool vx0 = (x0 >= 0) && (x0 < wi);
                bool vx1 = (x0+1 >= 0) && (x0+1 < wi);
                bool vy0 = (y0 >= 0) && (y0 < hi);
                bool vy1 = (y0+1 >= 0) && (y0+1 < hi);
                int cbase = h*32 + d;
                if (vy0 && vx0) acc += w00 * (float)vbase[((size_t)(base + y0*wi + x0))*CH + cbase];
                if (vy0 && vx1) acc += w10 * (float)vbase[((size_t)(base + y0*wi + x0 + 1))*CH + cbase];
                if (vy1 && vx0) acc += w01 * (float)vbase[((size_t)(base + (y0+1)*wi + x0))*CH + cbase];
                if (vy1 && vx1) acc += w11 * (float)vbase[((size_t)(base + (y0+1)*wi + x0 + 1))*CH + cbase];
            }
        }
        atomicAdd(&slots[(size_t)n*CH + h*32 + d], acc);   // mask==1 here
    }
}

// ---------------------------------------------------------------- K6: mask-mean + out proj + residual + LN
__global__ __launch_bounds__(256) void k_final(
    const float* __restrict__ slots, const float* __restrict__ maskf,
    const float* __restrict__ W_out, const float* __restrict__ b_out,
    const float* __restrict__ feature, const float* __restrict__ ln_g,
    const float* __restrict__ ln_b, float* __restrict__ out)
{
    __shared__ float ft[256*8];   // slots [k][q]
    __shared__ float yb[8*256];   // y [q][c]
    __shared__ float mu_s[8], rs_s[8];
    int t = threadIdx.x;
    int n0 = blockIdx.x * 8;
    #pragma unroll
    for (int q = 0; q < 8; q++) {
        int n = n0 + q;
        float msum = 0.f;
        #pragma unroll
        for (int cam = 0; cam < NCAMS; cam++) msum += maskf[cam*NQ + n];
        ft[t*8+q] = slots[(size_t)n*CH + t] / fmaxf(msum, 1.f);
    }
    __syncthreads();
    float y[8] = {};
    for (int k = 0; k < 256; k++) {
        float wv = W_out[k*CH + t];
        const float* fk = &ft[k*8];
        #pragma unroll
        for (int q = 0; q < 8; q++) y[q] += fk[q]*wv;
    }
    float bo = b_out[t];
    #pragma unroll
    for (int q = 0; q < 8; q++) {
        y[q] += bo + feature[(size_t)(n0+q)*CH + t];
        yb[q*256 + t] = y[q];
    }
    __syncthreads();
    int lane = t & 63, w = t >> 6;
    int q = w*2 + (lane >> 5);
    int l32 = lane & 31;
    float s = 0.f, s2 = 0.f;
    #pragma unroll
    for (int c = l32; c < 256; c += 32) {
        float v = yb[q*256 + c];
        s += v; s2 += v*v;
    }
    #pragma unroll
    for (int off = 16; off > 0; off >>= 1) {
        s  += __shfl_xor(s, off);
        s2 += __shfl_xor(s2, off);
    }
    if (l32 == 0) {
        float mu = s / 256.f;
        float var = s2 / 256.f - mu*mu;
        mu_s[q] = mu;
        rs_s[q] = rsqrtf(var + 1e-5f);
    }
    __syncthreads();
    float g = ln_g[t], bb = ln_b[t];
    #pragma unroll
    for (int qq = 0; qq < 8; qq++) {
        float v = (yb[qq*256 + t] - mu_s[qq]) * rs_s[qq] * g + bb;
        out[(size_t)(n0+qq)*CH + t] = v;
    }
}

// ---------------------------------------------------------------- launch
extern "C" void kernel_launch(void* const* d_in, const int* in_sizes, int n_in,
                              void* d_out, int out_size, void* d_ws, size_t ws_size,
                              hipStream_t stream)
{
    const float* means       = (const float*)d_in[0];
    const float* feature     = (const float*)d_in[1];
    const float* feat0       = (const float*)d_in[2];
    const float* feat1       = (const float*)d_in[3];
    const float* feat2       = (const float*)d_in[4];
    const float* cam2ego     = (const float*)d_in[5];
    const float* intrins     = (const float*)d_in[6];
    const float* post_rots   = (const float*)d_in[7];
    const float* post_trans  = (const float*)d_in[8];
    const float* W_off       = (const float*)d_in[9];
    const float* b_off       = (const float*)d_in[10];
    const float* W_attn      = (const float*)d_in[11];
    const float* b_attn      = (const float*)d_in[12];
    const float* W_val       = (const float*)d_in[13];
    const float* b_val       = (const float*)d_in[14];
    const float* W_out       = (const float*)d_in[15];
    const float* b_out       = (const float*)d_in[16];
    const float* cams_embeds = (const float*)d_in[17];
    const float* level_embeds= (const float*)d_in[18];
    const float* ln_g        = (const float*)d_in[19];
    const float* ln_b        = (const float*)d_in[20];
    const int*   img_h       = (const int*)d_in[21];
    const int*   img_w       = (const int*)d_in[22];

    // workspace layout (total 64,849,920 B = 61.9 MiB) — identical to R2 (guard passed => fits)
    char* ws = (char*)d_ws;
    float* coor  = (float*)(ws + 0);           //  6*6400*2 f32      =   307,200
    float* maskf = (float*)(ws + 307200);      //  6*6400 f32        =   153,600
    float* offs  = (float*)(ws + 460800);      //  6400*384 f32      = 9,830,400
    bf16*  attn  = (bf16*) (ws + 10291200);    //  6400*192 bf16     = 2,457,600
    bf16*  Wvp   = (bf16*) (ws + 12748800);    //  256*256 bf16      =   131,072
    float* slots = (float*)(ws + 12879872);    //  6400*256 f32      = 6,553,600
    bf16*  value = (bf16*) (ws + 19433472);    //  6*14784*256 bf16  = 45,416,448
    if (ws_size < 64849920u) return;

    k_zero   <<<1600, 256, 0, stream>>>(slots);
    k_proj   <<<150, 256, 0, stream>>>(means, cam2ego, intrins, post_rots, post_trans, img_h, img_w, coor, maskf);
    k_offattn<<<800, 256, 0, stream>>>(feature, W_off, b_off, W_attn, b_attn, offs, attn);
    k_pack   <<<32, 256, 0, stream>>>(W_val, Wvp);
    k_valproj<<<1386, 256, 0, stream>>>(feat0, feat1, feat2, cams_embeds, level_embeds, Wvp, b_val, value);
    k_msda   <<<9600, 256, 0, stream>>>(coor, offs, attn, value, maskf, slots);
    k_final  <<<800, 256, 0, stream>>>(slots, maskf, W_out, b_out, feature, ln_g, ln_b, (float*)d_out);
}

// Round 4
// 462.965 us; speedup vs baseline: 2.0870x; 2.0870x over previous
//
#include <hip/hip_runtime.h>
#include <hip/hip_bf16.h>

typedef __bf16 bf16;
typedef __attribute__((ext_vector_type(4))) float f32x4;
typedef __attribute__((ext_vector_type(8))) bf16 bf16x8;
typedef __attribute__((ext_vector_type(4))) bf16 bf16x4;

#define NCAMS 6
#define NQ 6400
#define CH 256
#define NH 8
#define NL 3
#define NP 8
#define S_TOT 14784   // 64*176 + 32*88 + 16*44

// ---------------------------------------------------------------- K0: zero the slots accumulator
__global__ __launch_bounds__(256) void k_zero(float* __restrict__ slots)
{
    int idx = blockIdx.x * 256 + threadIdx.x;
    reinterpret_cast<f32x4*>(slots)[idx] = (f32x4){0.f, 0.f, 0.f, 0.f};
}

// ---------------------------------------------------------------- K1: projection
__global__ __launch_bounds__(256) void k_proj(
    const float* __restrict__ means, const float* __restrict__ cam2ego,
    const float* __restrict__ intrins, const float* __restrict__ post_rots,
    const float* __restrict__ post_trans, const int* __restrict__ img_h,
    const int* __restrict__ img_w, float* __restrict__ coor, float* __restrict__ maskf)
{
    int idx = blockIdx.x * 256 + threadIdx.x;
    if (idx >= NCAMS * NQ) return;
    int cam = idx / NQ, n = idx % NQ;
    float mx = means[n*3+0], my = means[n*3+1], mz = means[n*3+2];
    const float* M = cam2ego + cam*16;
    float R[3][3], t[3];
    #pragma unroll
    for (int r = 0; r < 3; r++) {
        #pragma unroll
        for (int c = 0; c < 3; c++) R[r][c] = M[r*4+c];
        t[r] = M[r*4+3];
    }
    float dx = mx - t[0], dy = my - t[1], dz = mz - t[2];
    float xc = R[0][0]*dx + R[1][0]*dy + R[2][0]*dz;
    float yc = R[0][1]*dx + R[1][1]*dy + R[2][1]*dz;
    float zc = R[0][2]*dx + R[1][2]*dy + R[2][2]*dz;
    const float* K = intrins + cam*9;
    float ix = K[0]*xc + K[1]*yc + K[2]*zc;
    float iy = K[3]*xc + K[4]*yc + K[5]*zc;
    float iz = K[6]*xc + K[7]*yc + K[8]*zc;
    float px = ix / (iz + 1e-4f), py = iy / (iz + 1e-4f), pz = iz;
    const float* P = post_rots + cam*9;
    const float* T = post_trans + cam*3;
    float vx = P[0]*px + P[1]*py + P[2]*pz + T[0];
    float vy = P[3]*px + P[4]*py + P[5]*pz + T[1];
    float vz = P[6]*px + P[7]*py + P[8]*pz + T[2];
    float cx = vx / (float)img_w[0];
    float cy = vy / (float)img_h[0];
    bool ok = (vz > 0.01f) && (cx > 0.f) && (cx < 1.f) && (cy > 0.f) && (cy < 1.f);
    coor[idx*2+0] = cx;
    coor[idx*2+1] = cy;
    maskf[idx] = ok ? 1.f : 0.f;
}

// ---------------------------------------------------------------- K2: offsets + attn (+softmax)
__global__ __launch_bounds__(256) void k_offattn(
    const float* __restrict__ feature, const float* __restrict__ W_off,
    const float* __restrict__ b_off, const float* __restrict__ W_attn,
    const float* __restrict__ b_attn, float* __restrict__ offs, bf16* __restrict__ attn_out)
{
    __shared__ float ft[256*8];    // [k][q]
    __shared__ float lg[8*192];    // attn logits [q][a]
    int t = threadIdx.x;
    int n0 = blockIdx.x * 8;
    #pragma unroll
    for (int q = 0; q < 8; q++) ft[t*8+q] = feature[(size_t)(n0+q)*CH + t];
    __syncthreads();

    float a0[8] = {}, a1[8] = {}, a2[8] = {};
    for (int k = 0; k < 256; k++) {
        float w0 = W_off[k*384 + t];
        float w1 = (t < 128) ? W_off[k*384 + 256 + t] : W_attn[k*192 + (t-128)];
        float w2 = (t < 64) ? W_attn[k*192 + 128 + t] : 0.f;
        const float* fk = &ft[k*8];
        #pragma unroll
        for (int q = 0; q < 8; q++) {
            float f = fk[q];
            a0[q] += f*w0; a1[q] += f*w1; a2[q] += f*w2;
        }
    }
    float b0 = b_off[t];
    #pragma unroll
    for (int q = 0; q < 8; q++) offs[(size_t)(n0+q)*384 + t] = a0[q] + b0;
    if (t < 128) {
        float b1 = b_off[256 + t];
        #pragma unroll
        for (int q = 0; q < 8; q++) offs[(size_t)(n0+q)*384 + 256 + t] = a1[q] + b1;
    } else {
        float b1 = b_attn[t-128];
        #pragma unroll
        for (int q = 0; q < 8; q++) lg[q*192 + (t-128)] = a1[q] + b1;
    }
    if (t < 64) {
        float b2 = b_attn[128 + t];
        #pragma unroll
        for (int q = 0; q < 8; q++) lg[q*192 + 128 + t] = a2[q] + b2;
    }
    __syncthreads();
    if (t < 64) {
        int q = t >> 3, h = t & 7;
        const float* L = &lg[q*192 + h*24];
        float m = -1e30f;
        #pragma unroll
        for (int j = 0; j < 24; j++) m = fmaxf(m, L[j]);
        float e[24]; float s = 0.f;
        #pragma unroll
        for (int j = 0; j < 24; j++) { e[j] = __expf(L[j] - m); s += e[j]; }
        float inv = 1.f / s;
        #pragma unroll
        for (int j = 0; j < 24; j++) attn_out[(size_t)(n0+q)*192 + h*24 + j] = (bf16)(e[j]*inv);
    }
}

// ---------------------------------------------------------------- K3a: pack W_val into B-fragment order (bf16)
__global__ __launch_bounds__(256) void k_pack(const float* __restrict__ W_val, bf16* __restrict__ Wvp)
{
    int flat = blockIdx.x * 256 + threadIdx.x;   // (kc*16+nf)*64 + lane
    int kc = flat >> 10;
    int rem = flat & 1023;
    int nf = rem >> 6;
    int lane = rem & 63;
    int q = lane >> 4;
    int col = nf*16 + (lane & 15);
    bf16x8 v;
    #pragma unroll
    for (int j = 0; j < 8; j++) v[j] = (bf16)W_val[(size_t)(kc*32 + q*8 + j)*256 + col];
    *reinterpret_cast<bf16x8*>(Wvp + (size_t)flat*8) = v;
}

// ---------------------------------------------------------------- K3: value projection GEMM (MFMA bf16)
// value layout: [cam][head][pos][32ch]  (bf16)
__global__ __launch_bounds__(256) void k_valproj(
    const float* __restrict__ f0, const float* __restrict__ f1, const float* __restrict__ f2,
    const float* __restrict__ cams_embeds, const float* __restrict__ level_embeds,
    const bf16* __restrict__ Wvp, const float* __restrict__ b_val, bf16* __restrict__ value)
{
    __shared__ alignas(16) bf16 A[64][48];   // [m][k], padded row 48
    int bi = blockIdx.x;
    int cam = bi / 231, mb = bi % 231;
    int lvl, local0, HW;
    const float* fp;
    if (mb < 176)      { lvl = 0; local0 = mb*64;        fp = f0; HW = 11264; }
    else if (mb < 220) { lvl = 1; local0 = (mb-176)*64;  fp = f1; HW = 2816;  }
    else               { lvl = 2; local0 = (mb-220)*64;  fp = f2; HW = 704;   }
    int pos0 = (lvl == 0 ? 0 : (lvl == 1 ? 11264 : 14080)) + local0;
    const float* featbase = fp + (size_t)cam*CH*HW + local0;

    int t = threadIdx.x;
    int lane = t & 63, w = t >> 6;
    int kk = t >> 3;            // 0..31 (channel within chunk)
    int m8 = (t & 7) * 8;       // m start
    int q = lane >> 4, r16 = lane & 15;

    f32x4 acc[4][4];
    #pragma unroll
    for (int i = 0; i < 4; i++)
        #pragma unroll
        for (int j = 0; j < 4; j++) acc[i][j] = (f32x4){0.f,0.f,0.f,0.f};

    for (int kc = 0; kc < 8; kc++) {
        __syncthreads();
        int kg = kc*32 + kk;
        float e = cams_embeds[cam*CH + kg] + level_embeds[lvl*CH + kg];
        f32x4 v0 = *reinterpret_cast<const f32x4*>(featbase + (size_t)kg*HW + m8);
        f32x4 v1 = *reinterpret_cast<const f32x4*>(featbase + (size_t)kg*HW + m8 + 4);
        #pragma unroll
        for (int i = 0; i < 4; i++) A[m8+i][kk]   = (bf16)(v0[i] + e);
        #pragma unroll
        for (int i = 0; i < 4; i++) A[m8+4+i][kk] = (bf16)(v1[i] + e);
        __syncthreads();

        bf16x8 bfr[4];
        #pragma unroll
        for (int nf = 0; nf < 4; nf++) {
            int nfg = w*4 + nf;
            bfr[nf] = *reinterpret_cast<const bf16x8*>(Wvp + ((size_t)(kc*16 + nfg)*64 + lane)*8);
        }
        #pragma unroll
        for (int mf = 0; mf < 4; mf++) {
            bf16x8 afr = *reinterpret_cast<const bf16x8*>(&A[mf*16 + r16][q*8]);
            #pragma unroll
            for (int nf = 0; nf < 4; nf++)
                acc[mf][nf] = __builtin_amdgcn_mfma_f32_16x16x32_bf16(afr, bfr[nf], acc[mf][nf], 0, 0, 0);
        }
    }
    // epilogue: D[row=(lane>>4)*4+r][col=lane&15]; write to [cam][head][pos][32]
    #pragma unroll
    for (int mf = 0; mf < 4; mf++) {
        #pragma unroll
        for (int nf = 0; nf < 4; nf++) {
            int c = w*64 + nf*16 + r16;
            int head = c >> 5, ch = c & 31;
            float bv = b_val[c];
            #pragma unroll
            for (int r = 0; r < 4; r++) {
                int srow = pos0 + mf*16 + q*4 + r;
                value[((size_t)(cam*NH + head)*S_TOT + srow)*32 + ch] = (bf16)(acc[mf][nf][r] + bv);
            }
        }
    }
}

// ---------------------------------------------------------------- K4: MSDA gather, two-phase
// Phase 1: one sample per lane -> weights*attn (validity-zeroed) + clamped corner offsets into LDS
// Phase 2: lane = p*8 + k : 8 points in flight, bf16x4 channel loads, xor-reduce over p
__global__ __launch_bounds__(256) void k_msda(
    const float* __restrict__ coor, const float* __restrict__ offs,
    const bf16* __restrict__ attn, const bf16* __restrict__ value,
    const float* __restrict__ maskf, float* __restrict__ slots)
{
    __shared__ f32x4 s_w[4][192];
    __shared__ int4  s_o[4][192];
    int wv = threadIdx.x >> 6;
    int lane = threadIdx.x & 63;
    int wid = blockIdx.x * 4 + wv;
    int cam = wid % NCAMS;
    int n = wid / NCAMS;
    float msk = maskf[cam*NQ + n];

    if (msk != 0.f) {
        float cx = coor[(cam*NQ + n)*2 + 0];
        float cy = coor[(cam*NQ + n)*2 + 1];
        #pragma unroll
        for (int b = 0; b < 3; b++) {
            int mm = b*64 + lane;               // sample id = (h*3+lvl)*8+p
            int h = mm / 24;
            int r = mm - h*24;
            int lvl = r >> 3;
            float aw = (float)attn[(size_t)n*192 + mm];
            float ox = offs[(size_t)n*384 + mm*2];
            float oy = offs[(size_t)n*384 + mm*2 + 1];
            int wi   = (lvl == 0) ? 176 : ((lvl == 1) ? 88 : 44);
            int hi   = (lvl == 0) ? 64  : ((lvl == 1) ? 32 : 16);
            int base = (lvl == 0) ? 0   : ((lvl == 1) ? 11264 : 14080);
            float x = cx*(float)wi + ox - 0.5f;
            float y = cy*(float)hi + oy - 0.5f;
            float xf = floorf(x), yf = floorf(y);
            float tx = x - xf, ty = y - yf;
            float wm1x = (float)(wi-1), wm1y = (float)(hi-1);
            bool vx0 = (xf >= 0.f)      && (xf <= wm1x);
            bool vx1 = (xf+1.f >= 0.f)  && (xf+1.f <= wm1x);
            bool vy0 = (yf >= 0.f)      && (yf <= wm1y);
            bool vy1 = (yf+1.f >= 0.f)  && (yf+1.f <= wm1y);
            int x0 = (int)fminf(fmaxf(xf,      0.f), wm1x);
            int x1 = (int)fminf(fmaxf(xf+1.f,  0.f), wm1x);
            int y0 = (int)fminf(fmaxf(yf,      0.f), wm1y);
            int y1 = (int)fminf(fmaxf(yf+1.f,  0.f), wm1y);
            float w00 = (1.f-tx)*(1.f-ty)*aw * ((vx0 && vy0) ? 1.f : 0.f);
            float w10 = tx*(1.f-ty)*aw       * ((vx1 && vy0) ? 1.f : 0.f);
            float w01 = (1.f-tx)*ty*aw       * ((vx0 && vy1) ? 1.f : 0.f);
            float w11 = tx*ty*aw             * ((vx1 && vy1) ? 1.f : 0.f);
            int rowb = (cam*NH + h)*S_TOT + base;
            int r0 = rowb + y0*wi, r1 = rowb + y1*wi;
            s_w[wv][mm] = (f32x4){w00, w10, w01, w11};
            s_o[wv][mm] = make_int4((r0 + x0)*32, (r0 + x1)*32, (r1 + x0)*32, (r1 + x1)*32);
        }
    }
    __syncthreads();
    if (msk == 0.f) return;

    int p = lane >> 3, k = lane & 7;
    int k4 = k*4;
    for (int h = 0; h < NH; h++) {
        f32x4 acc = (f32x4){0.f, 0.f, 0.f, 0.f};
        #pragma unroll
        for (int lvl = 0; lvl < 3; lvl++) {
            int mm = h*24 + lvl*8 + p;
            f32x4 w4 = s_w[wv][mm];
            int4  o4 = s_o[wv][mm];
            bf16x4 v00 = *reinterpret_cast<const bf16x4*>(value + o4.x + k4);
            bf16x4 v10 = *reinterpret_cast<const bf16x4*>(value + o4.y + k4);
            bf16x4 v01 = *reinterpret_cast<const bf16x4*>(value + o4.z + k4);
            bf16x4 v11 = *reinterpret_cast<const bf16x4*>(value + o4.w + k4);
            #pragma unroll
            for (int i = 0; i < 4; i++)
                acc[i] += w4.x*(float)v00[i] + w4.y*(float)v10[i]
                        + w4.z*(float)v01[i] + w4.w*(float)v11[i];
        }
        #pragma unroll
        for (int i = 0; i < 4; i++) {
            acc[i] += __shfl_xor(acc[i], 8);
            acc[i] += __shfl_xor(acc[i], 16);
            acc[i] += __shfl_xor(acc[i], 32);
        }
        if (p == 0) {
            float* dst = &slots[(size_t)n*CH + h*32 + k4];
            #pragma unroll
            for (int i = 0; i < 4; i++) atomicAdd(dst + i, acc[i]);
        }
    }
}

// ---------------------------------------------------------------- K6: mask-mean + out proj + residual + LN
__global__ __launch_bounds__(256) void k_final(
    const float* __restrict__ slots, const float* __restrict__ maskf,
    const float* __restrict__ W_out, const float* __restrict__ b_out,
    const float* __restrict__ feature, const float* __restrict__ ln_g,
    const float* __restrict__ ln_b, float* __restrict__ out)
{
    __shared__ float ft[256*8];   // slots [k][q]
    __shared__ float yb[8*256];   // y [q][c]
    __shared__ float mu_s[8], rs_s[8];
    int t = threadIdx.x;
    int n0 = blockIdx.x * 8;
    #pragma unroll
    for (int q = 0; q < 8; q++) {
        int n = n0 + q;
        float msum = 0.f;
        #pragma unroll
        for (int cam = 0; cam < NCAMS; cam++) msum += maskf[cam*NQ + n];
        ft[t*8+q] = slots[(size_t)n*CH + t] / fmaxf(msum, 1.f);
    }
    __syncthreads();
    float y[8] = {};
    for (int k = 0; k < 256; k++) {
        float wv = W_out[k*CH + t];
        const float* fk = &ft[k*8];
        #pragma unroll
        for (int q = 0; q < 8; q++) y[q] += fk[q]*wv;
    }
    float bo = b_out[t];
    #pragma unroll
    for (int q = 0; q < 8; q++) {
        y[q] += bo + feature[(size_t)(n0+q)*CH + t];
        yb[q*256 + t] = y[q];
    }
    __syncthreads();
    int lane = t & 63, w = t >> 6;
    int q = w*2 + (lane >> 5);
    int l32 = lane & 31;
    float s = 0.f, s2 = 0.f;
    #pragma unroll
    for (int c = l32; c < 256; c += 32) {
        float v = yb[q*256 + c];
        s += v; s2 += v*v;
    }
    #pragma unroll
    for (int off = 16; off > 0; off >>= 1) {
        s  += __shfl_xor(s, off);
        s2 += __shfl_xor(s2, off);
    }
    if (l32 == 0) {
        float mu = s / 256.f;
        float var = s2 / 256.f - mu*mu;
        mu_s[q] = mu;
        rs_s[q] = rsqrtf(var + 1e-5f);
    }
    __syncthreads();
    float g = ln_g[t], bb = ln_b[t];
    #pragma unroll
    for (int qq = 0; qq < 8; qq++) {
        float v = (yb[qq*256 + t] - mu_s[qq]) * rs_s[qq] * g + bb;
        out[(size_t)(n0+qq)*CH + t] = v;
    }
}

// ---------------------------------------------------------------- launch
extern "C" void kernel_launch(void* const* d_in, const int* in_sizes, int n_in,
                              void* d_out, int out_size, void* d_ws, size_t ws_size,
                              hipStream_t stream)
{
    const float* means       = (const float*)d_in[0];
    const float* feature     = (const float*)d_in[1];
    const float* feat0       = (const float*)d_in[2];
    const float* feat1       = (const float*)d_in[3];
    const float* feat2       = (const float*)d_in[4];
    const float* cam2ego     = (const float*)d_in[5];
    const float* intrins     = (const float*)d_in[6];
    const float* post_rots   = (const float*)d_in[7];
    const float* post_trans  = (const float*)d_in[8];
    const float* W_off       = (const float*)d_in[9];
    const float* b_off       = (const float*)d_in[10];
    const float* W_attn      = (const float*)d_in[11];
    const float* b_attn      = (const float*)d_in[12];
    const float* W_val       = (const float*)d_in[13];
    const float* b_val       = (const float*)d_in[14];
    const float* W_out       = (const float*)d_in[15];
    const float* b_out       = (const float*)d_in[16];
    const float* cams_embeds = (const float*)d_in[17];
    const float* level_embeds= (const float*)d_in[18];
    const float* ln_g        = (const float*)d_in[19];
    const float* ln_b        = (const float*)d_in[20];
    const int*   img_h       = (const int*)d_in[21];
    const int*   img_w       = (const int*)d_in[22];

    // workspace layout (total 64,849,920 B = 61.9 MiB)
    char* ws = (char*)d_ws;
    float* coor  = (float*)(ws + 0);           //  6*6400*2 f32      =   307,200
    float* maskf = (float*)(ws + 307200);      //  6*6400 f32        =   153,600
    float* offs  = (float*)(ws + 460800);      //  6400*384 f32      = 9,830,400
    bf16*  attn  = (bf16*) (ws + 10291200);    //  6400*192 bf16     = 2,457,600
    bf16*  Wvp   = (bf16*) (ws + 12748800);    //  256*256 bf16      =   131,072
    float* slots = (float*)(ws + 12879872);    //  6400*256 f32      = 6,553,600
    bf16*  value = (bf16*) (ws + 19433472);    //  6*8*14784*32 bf16 = 45,416,448
    if (ws_size < 64849920u) return;

    k_zero   <<<1600, 256, 0, stream>>>(slots);
    k_proj   <<<150, 256, 0, stream>>>(means, cam2ego, intrins, post_rots, post_trans, img_h, img_w, coor, maskf);
    k_offattn<<<800, 256, 0, stream>>>(feature, W_off, b_off, W_attn, b_attn, offs, attn);
    k_pack   <<<32, 256, 0, stream>>>(W_val, Wvp);
    k_valproj<<<1386, 256, 0, stream>>>(feat0, feat1, feat2, cams_embeds, level_embeds, Wvp, b_val, value);
    k_msda   <<<9600, 256, 0, stream>>>(coor, offs, attn, value, maskf, slots);
    k_final  <<<800, 256, 0, stream>>>(slots, maskf, W_out, b_out, feature, ln_g, ln_b, (float*)d_out);
}

// Round 5
// 418.869 us; speedup vs baseline: 2.3067x; 1.1053x over previous
//
#include <hip/hip_runtime.h>
#include <hip/hip_bf16.h>

typedef __bf16 bf16;
typedef __attribute__((ext_vector_type(4))) float f32x4;
typedef __attribute__((ext_vector_type(8))) bf16 bf16x8;
typedef __attribute__((ext_vector_type(4))) bf16 bf16x4;

#define NCAMS 6
#define NQ 6400
#define CH 256
#define NH 8
#define NL 3
#define NP 8
#define S_TOT 14784   // 64*176 + 32*88 + 16*44

// ---------------------------------------------------------------- K1: projection
__global__ __launch_bounds__(256) void k_proj(
    const float* __restrict__ means, const float* __restrict__ cam2ego,
    const float* __restrict__ intrins, const float* __restrict__ post_rots,
    const float* __restrict__ post_trans, const int* __restrict__ img_h,
    const int* __restrict__ img_w, float* __restrict__ coor, float* __restrict__ maskf)
{
    int idx = blockIdx.x * 256 + threadIdx.x;
    if (idx >= NCAMS * NQ) return;
    int cam = idx / NQ, n = idx % NQ;
    float mx = means[n*3+0], my = means[n*3+1], mz = means[n*3+2];
    const float* M = cam2ego + cam*16;
    float R[3][3], t[3];
    #pragma unroll
    for (int r = 0; r < 3; r++) {
        #pragma unroll
        for (int c = 0; c < 3; c++) R[r][c] = M[r*4+c];
        t[r] = M[r*4+3];
    }
    float dx = mx - t[0], dy = my - t[1], dz = mz - t[2];
    float xc = R[0][0]*dx + R[1][0]*dy + R[2][0]*dz;
    float yc = R[0][1]*dx + R[1][1]*dy + R[2][1]*dz;
    float zc = R[0][2]*dx + R[1][2]*dy + R[2][2]*dz;
    const float* K = intrins + cam*9;
    float ix = K[0]*xc + K[1]*yc + K[2]*zc;
    float iy = K[3]*xc + K[4]*yc + K[5]*zc;
    float iz = K[6]*xc + K[7]*yc + K[8]*zc;
    float px = ix / (iz + 1e-4f), py = iy / (iz + 1e-4f), pz = iz;
    const float* P = post_rots + cam*9;
    const float* T = post_trans + cam*3;
    float vx = P[0]*px + P[1]*py + P[2]*pz + T[0];
    float vy = P[3]*px + P[4]*py + P[5]*pz + T[1];
    float vz = P[6]*px + P[7]*py + P[8]*pz + T[2];
    float cx = vx / (float)img_w[0];
    float cy = vy / (float)img_h[0];
    bool ok = (vz > 0.01f) && (cx > 0.f) && (cx < 1.f) && (cy > 0.f) && (cy < 1.f);
    coor[idx*2+0] = cx;
    coor[idx*2+1] = cy;
    maskf[idx] = ok ? 1.f : 0.f;
}

// ---------------------------------------------------------------- K2: offsets + attn (+softmax)
__global__ __launch_bounds__(256) void k_offattn(
    const float* __restrict__ feature, const float* __restrict__ W_off,
    const float* __restrict__ b_off, const float* __restrict__ W_attn,
    const float* __restrict__ b_attn, float* __restrict__ offs, bf16* __restrict__ attn_out)
{
    __shared__ float ft[256*8];    // [k][q]
    __shared__ float lg[8*192];    // attn logits [q][a]
    int t = threadIdx.x;
    int n0 = blockIdx.x * 8;
    #pragma unroll
    for (int q = 0; q < 8; q++) ft[t*8+q] = feature[(size_t)(n0+q)*CH + t];
    __syncthreads();

    float a0[8] = {}, a1[8] = {}, a2[8] = {};
    for (int k = 0; k < 256; k++) {
        float w0 = W_off[k*384 + t];
        float w1 = (t < 128) ? W_off[k*384 + 256 + t] : W_attn[k*192 + (t-128)];
        float w2 = (t < 64) ? W_attn[k*192 + 128 + t] : 0.f;
        const float* fk = &ft[k*8];
        #pragma unroll
        for (int q = 0; q < 8; q++) {
            float f = fk[q];
            a0[q] += f*w0; a1[q] += f*w1; a2[q] += f*w2;
        }
    }
    float b0 = b_off[t];
    #pragma unroll
    for (int q = 0; q < 8; q++) offs[(size_t)(n0+q)*384 + t] = a0[q] + b0;
    if (t < 128) {
        float b1 = b_off[256 + t];
        #pragma unroll
        for (int q = 0; q < 8; q++) offs[(size_t)(n0+q)*384 + 256 + t] = a1[q] + b1;
    } else {
        float b1 = b_attn[t-128];
        #pragma unroll
        for (int q = 0; q < 8; q++) lg[q*192 + (t-128)] = a1[q] + b1;
    }
    if (t < 64) {
        float b2 = b_attn[128 + t];
        #pragma unroll
        for (int q = 0; q < 8; q++) lg[q*192 + 128 + t] = a2[q] + b2;
    }
    __syncthreads();
    if (t < 64) {
        int q = t >> 3, h = t & 7;
        const float* L = &lg[q*192 + h*24];
        float m = -1e30f;
        #pragma unroll
        for (int j = 0; j < 24; j++) m = fmaxf(m, L[j]);
        float e[24]; float s = 0.f;
        #pragma unroll
        for (int j = 0; j < 24; j++) { e[j] = __expf(L[j] - m); s += e[j]; }
        float inv = 1.f / s;
        #pragma unroll
        for (int j = 0; j < 24; j++) attn_out[(size_t)(n0+q)*192 + h*24 + j] = (bf16)(e[j]*inv);
    }
}

// ---------------------------------------------------------------- K3a: pack W_val into B-fragment order (bf16)
__global__ __launch_bounds__(256) void k_pack(const float* __restrict__ W_val, bf16* __restrict__ Wvp)
{
    int flat = blockIdx.x * 256 + threadIdx.x;   // (kc*16+nf)*64 + lane
    int kc = flat >> 10;
    int rem = flat & 1023;
    int nf = rem >> 6;
    int lane = rem & 63;
    int q = lane >> 4;
    int col = nf*16 + (lane & 15);
    bf16x8 v;
    #pragma unroll
    for (int j = 0; j < 8; j++) v[j] = (bf16)W_val[(size_t)(kc*32 + q*8 + j)*256 + col];
    *reinterpret_cast<bf16x8*>(Wvp + (size_t)flat*8) = v;
}

// ---------------------------------------------------------------- K3: value projection GEMM (MFMA bf16)
// value layout: [cam][head][pos][32ch]  (bf16)
__global__ __launch_bounds__(256) void k_valproj(
    const float* __restrict__ f0, const float* __restrict__ f1, const float* __restrict__ f2,
    const float* __restrict__ cams_embeds, const float* __restrict__ level_embeds,
    const bf16* __restrict__ Wvp, const float* __restrict__ b_val, bf16* __restrict__ value)
{
    __shared__ alignas(16) bf16 A[64][48];   // [m][k], padded row 48
    int bi = blockIdx.x;
    int cam = bi / 231, mb = bi % 231;
    int lvl, local0, HW;
    const float* fp;
    if (mb < 176)      { lvl = 0; local0 = mb*64;        fp = f0; HW = 11264; }
    else if (mb < 220) { lvl = 1; local0 = (mb-176)*64;  fp = f1; HW = 2816;  }
    else               { lvl = 2; local0 = (mb-220)*64;  fp = f2; HW = 704;   }
    int pos0 = (lvl == 0 ? 0 : (lvl == 1 ? 11264 : 14080)) + local0;
    const float* featbase = fp + (size_t)cam*CH*HW + local0;

    int t = threadIdx.x;
    int lane = t & 63, w = t >> 6;
    int kk = t >> 3;            // 0..31 (channel within chunk)
    int m8 = (t & 7) * 8;       // m start
    int q = lane >> 4, r16 = lane & 15;

    f32x4 acc[4][4];
    #pragma unroll
    for (int i = 0; i < 4; i++)
        #pragma unroll
        for (int j = 0; j < 4; j++) acc[i][j] = (f32x4){0.f,0.f,0.f,0.f};

    for (int kc = 0; kc < 8; kc++) {
        __syncthreads();
        int kg = kc*32 + kk;
        float e = cams_embeds[cam*CH + kg] + level_embeds[lvl*CH + kg];
        f32x4 v0 = *reinterpret_cast<const f32x4*>(featbase + (size_t)kg*HW + m8);
        f32x4 v1 = *reinterpret_cast<const f32x4*>(featbase + (size_t)kg*HW + m8 + 4);
        #pragma unroll
        for (int i = 0; i < 4; i++) A[m8+i][kk]   = (bf16)(v0[i] + e);
        #pragma unroll
        for (int i = 0; i < 4; i++) A[m8+4+i][kk] = (bf16)(v1[i] + e);
        __syncthreads();

        bf16x8 bfr[4];
        #pragma unroll
        for (int nf = 0; nf < 4; nf++) {
            int nfg = w*4 + nf;
            bfr[nf] = *reinterpret_cast<const bf16x8*>(Wvp + ((size_t)(kc*16 + nfg)*64 + lane)*8);
        }
        #pragma unroll
        for (int mf = 0; mf < 4; mf++) {
            bf16x8 afr = *reinterpret_cast<const bf16x8*>(&A[mf*16 + r16][q*8]);
            #pragma unroll
            for (int nf = 0; nf < 4; nf++)
                acc[mf][nf] = __builtin_amdgcn_mfma_f32_16x16x32_bf16(afr, bfr[nf], acc[mf][nf], 0, 0, 0);
        }
    }
    // epilogue: D[row=(lane>>4)*4+r][col=lane&15]; write to [cam][head][pos][32]
    #pragma unroll
    for (int mf = 0; mf < 4; mf++) {
        #pragma unroll
        for (int nf = 0; nf < 4; nf++) {
            int c = w*64 + nf*16 + r16;
            int head = c >> 5, ch = c & 31;
            float bv = b_val[c];
            #pragma unroll
            for (int r = 0; r < 4; r++) {
                int srow = pos0 + mf*16 + q*4 + r;
                value[((size_t)(cam*NH + head)*S_TOT + srow)*32 + ch] = (bf16)(acc[mf][nf][r] + bv);
            }
        }
    }
}

// ---------------------------------------------------------------- K4: MSDA gather
// One wave per query; cam loop inside; no atomics, no __syncthreads.
// Phase 1 (per cam): one sample per lane (3 rounds) -> attn*validity-premultiplied
//   bilinear weights + corner BYTE offsets into wave-private LDS.
// Phase 2 (per cam): lane = p*8+k: 8 points in flight, uint2 (4 bf16 ch) loads,
//   bit-unpack bf16->f32, fma into per-head register accumulators.
// Final: xor-reduce over p, plain f32x4 store to slots.
__global__ __launch_bounds__(256) void k_msda(
    const float* __restrict__ coor, const float* __restrict__ offs,
    const bf16* __restrict__ attn, const bf16* __restrict__ value,
    const float* __restrict__ maskf, float* __restrict__ slots)
{
    __shared__ f32x4 s_w[4][192];
    __shared__ int4  s_o[4][192];
    int wv = threadIdx.x >> 6;
    int lane = threadIdx.x & 63;
    int n = blockIdx.x * 4 + wv;
    int p = lane >> 3, k = lane & 7;
    int kb = k * 8;                          // byte offset of this lane's 4 channels

    // hoist per-query sample params (reused by all cams)
    float oxr[3], oyr[3], awr[3];
    #pragma unroll
    for (int b = 0; b < 3; b++) {
        int mm = b*64 + lane;                // sample id = (h*3+lvl)*8+p
        float2 o2 = *reinterpret_cast<const float2*>(offs + (size_t)n*384 + mm*2);
        oxr[b] = o2.x; oyr[b] = o2.y;
        awr[b] = (float)attn[(size_t)n*192 + mm];
    }

    f32x4 acc[NH];
    #pragma unroll
    for (int h = 0; h < NH; h++) acc[h] = (f32x4){0.f, 0.f, 0.f, 0.f};

    const char* vbyte = (const char*)value;

    for (int cam = 0; cam < NCAMS; cam++) {
        if (maskf[cam*NQ + n] == 0.f) continue;
        float cx = coor[(cam*NQ + n)*2 + 0];
        float cy = coor[(cam*NQ + n)*2 + 1];

        #pragma unroll
        for (int b = 0; b < 3; b++) {
            int mm = b*64 + lane;
            int h = mm / 24;
            int r = mm - h*24;
            int lvl = r >> 3;
            int wi   = (lvl == 0) ? 176 : ((lvl == 1) ? 88 : 44);
            int hi   = (lvl == 0) ? 64  : ((lvl == 1) ? 32 : 16);
            int base = (lvl == 0) ? 0   : ((lvl == 1) ? 11264 : 14080);
            float x = cx*(float)wi + oxr[b] - 0.5f;
            float y = cy*(float)hi + oyr[b] - 0.5f;
            float xf = floorf(x), yf = floorf(y);
            float tx = x - xf, ty = y - yf;
            float wm1x = (float)(wi-1), wm1y = (float)(hi-1);
            bool vx0 = (xf >= 0.f)      && (xf <= wm1x);
            bool vx1 = (xf+1.f >= 0.f)  && (xf+1.f <= wm1x);
            bool vy0 = (yf >= 0.f)      && (yf <= wm1y);
            bool vy1 = (yf+1.f >= 0.f)  && (yf+1.f <= wm1y);
            int x0 = (int)fminf(fmaxf(xf,      0.f), wm1x);
            int x1 = (int)fminf(fmaxf(xf+1.f,  0.f), wm1x);
            int y0 = (int)fminf(fmaxf(yf,      0.f), wm1y);
            int y1 = (int)fminf(fmaxf(yf+1.f,  0.f), wm1y);
            float aw = awr[b];
            float w00 = (1.f-tx)*(1.f-ty)*aw * ((vx0 && vy0) ? 1.f : 0.f);
            float w10 = tx*(1.f-ty)*aw       * ((vx1 && vy0) ? 1.f : 0.f);
            float w01 = (1.f-tx)*ty*aw       * ((vx0 && vy1) ? 1.f : 0.f);
            float w11 = tx*ty*aw             * ((vx1 && vy1) ? 1.f : 0.f);
            int rowb = (cam*NH + h)*S_TOT + base;
            int r0 = rowb + y0*wi, r1 = rowb + y1*wi;
            s_w[wv][mm] = (f32x4){w00, w10, w01, w11};
            s_o[wv][mm] = make_int4((r0 + x0)*64, (r0 + x1)*64, (r1 + x0)*64, (r1 + x1)*64);
        }
        // wave-private LDS: compiler-inserted lgkmcnt ordering, no barrier needed

        #pragma unroll
        for (int h = 0; h < NH; h++) {
            #pragma unroll
            for (int lvl = 0; lvl < 3; lvl++) {
                int mm = h*24 + lvl*8 + p;
                f32x4 w4 = s_w[wv][mm];
                int4  o4 = s_o[wv][mm];
                uint2 d00 = *reinterpret_cast<const uint2*>(vbyte + (o4.x + kb));
                uint2 d10 = *reinterpret_cast<const uint2*>(vbyte + (o4.y + kb));
                uint2 d01 = *reinterpret_cast<const uint2*>(vbyte + (o4.z + kb));
                uint2 d11 = *reinterpret_cast<const uint2*>(vbyte + (o4.w + kb));
                acc[h][0] = fmaf(__uint_as_float(d00.x << 16),          w4.x, acc[h][0]);
                acc[h][1] = fmaf(__uint_as_float(d00.x & 0xffff0000u),  w4.x, acc[h][1]);
                acc[h][2] = fmaf(__uint_as_float(d00.y << 16),          w4.x, acc[h][2]);
                acc[h][3] = fmaf(__uint_as_float(d00.y & 0xffff0000u),  w4.x, acc[h][3]);
                acc[h][0] = fmaf(__uint_as_float(d10.x << 16),          w4.y, acc[h][0]);
                acc[h][1] = fmaf(__uint_as_float(d10.x & 0xffff0000u),  w4.y, acc[h][1]);
                acc[h][2] = fmaf(__uint_as_float(d10.y << 16),          w4.y, acc[h][2]);
                acc[h][3] = fmaf(__uint_as_float(d10.y & 0xffff0000u),  w4.y, acc[h][3]);
                acc[h][0] = fmaf(__uint_as_float(d01.x << 16),          w4.z, acc[h][0]);
                acc[h][1] = fmaf(__uint_as_float(d01.x & 0xffff0000u),  w4.z, acc[h][1]);
                acc[h][2] = fmaf(__uint_as_float(d01.y << 16),          w4.z, acc[h][2]);
                acc[h][3] = fmaf(__uint_as_float(d01.y & 0xffff0000u),  w4.z, acc[h][3]);
                acc[h][0] = fmaf(__uint_as_float(d11.x << 16),          w4.w, acc[h][0]);
                acc[h][1] = fmaf(__uint_as_float(d11.x & 0xffff0000u),  w4.w, acc[h][1]);
                acc[h][2] = fmaf(__uint_as_float(d11.y << 16),          w4.w, acc[h][2]);
                acc[h][3] = fmaf(__uint_as_float(d11.y & 0xffff0000u),  w4.w, acc[h][3]);
            }
        }
    }

    // reduce over p (8 lanes), then lane group p==0 owns channels k*4..k*4+3
    #pragma unroll
    for (int h = 0; h < NH; h++)
        #pragma unroll
        for (int i = 0; i < 4; i++) {
            acc[h][i] += __shfl_xor(acc[h][i], 8);
            acc[h][i] += __shfl_xor(acc[h][i], 16);
            acc[h][i] += __shfl_xor(acc[h][i], 32);
        }
    if (p == 0) {
        #pragma unroll
        for (int h = 0; h < NH; h++)
            *reinterpret_cast<f32x4*>(slots + (size_t)n*CH + h*32 + k*4) = acc[h];
    }
}

// ---------------------------------------------------------------- K6: mask-mean + out proj + residual + LN
__global__ __launch_bounds__(256) void k_final(
    const float* __restrict__ slots, const float* __restrict__ maskf,
    const float* __restrict__ W_out, const float* __restrict__ b_out,
    const float* __restrict__ feature, const float* __restrict__ ln_g,
    const float* __restrict__ ln_b, float* __restrict__ out)
{
    __shared__ float ft[256*8];   // slots [k][q]
    __shared__ float yb[8*256];   // y [q][c]
    __shared__ float mu_s[8], rs_s[8];
    int t = threadIdx.x;
    int n0 = blockIdx.x * 8;
    #pragma unroll
    for (int q = 0; q < 8; q++) {
        int n = n0 + q;
        float msum = 0.f;
        #pragma unroll
        for (int cam = 0; cam < NCAMS; cam++) msum += maskf[cam*NQ + n];
        ft[t*8+q] = slots[(size_t)n*CH + t] / fmaxf(msum, 1.f);
    }
    __syncthreads();
    float y[8] = {};
    for (int k = 0; k < 256; k++) {
        float wv = W_out[k*CH + t];
        const float* fk = &ft[k*8];
        #pragma unroll
        for (int q = 0; q < 8; q++) y[q] += fk[q]*wv;
    }
    float bo = b_out[t];
    #pragma unroll
    for (int q = 0; q < 8; q++) {
        y[q] += bo + feature[(size_t)(n0+q)*CH + t];
        yb[q*256 + t] = y[q];
    }
    __syncthreads();
    int lane = t & 63, w = t >> 6;
    int q = w*2 + (lane >> 5);
    int l32 = lane & 31;
    float s = 0.f, s2 = 0.f;
    #pragma unroll
    for (int c = l32; c < 256; c += 32) {
        float v = yb[q*256 + c];
        s += v; s2 += v*v;
    }
    #pragma unroll
    for (int off = 16; off > 0; off >>= 1) {
        s  += __shfl_xor(s, off);
        s2 += __shfl_xor(s2, off);
    }
    if (l32 == 0) {
        float mu = s / 256.f;
        float var = s2 / 256.f - mu*mu;
        mu_s[q] = mu;
        rs_s[q] = rsqrtf(var + 1e-5f);
    }
    __syncthreads();
    float g = ln_g[t], bb = ln_b[t];
    #pragma unroll
    for (int qq = 0; qq < 8; qq++) {
        float v = (yb[qq*256 + t] - mu_s[qq]) * rs_s[qq] * g + bb;
        out[(size_t)(n0+qq)*CH + t] = v;
    }
}

// ---------------------------------------------------------------- launch
extern "C" void kernel_launch(void* const* d_in, const int* in_sizes, int n_in,
                              void* d_out, int out_size, void* d_ws, size_t ws_size,
                              hipStream_t stream)
{
    const float* means       = (const float*)d_in[0];
    const float* feature     = (const float*)d_in[1];
    const float* feat0       = (const float*)d_in[2];
    const float* feat1       = (const float*)d_in[3];
    const float* feat2       = (const float*)d_in[4];
    const float* cam2ego     = (const float*)d_in[5];
    const float* intrins     = (const float*)d_in[6];
    const float* post_rots   = (const float*)d_in[7];
    const float* post_trans  = (const float*)d_in[8];
    const float* W_off       = (const float*)d_in[9];
    const float* b_off       = (const float*)d_in[10];
    const float* W_attn      = (const float*)d_in[11];
    const float* b_attn      = (const float*)d_in[12];
    const float* W_val       = (const float*)d_in[13];
    const float* b_val       = (const float*)d_in[14];
    const float* W_out       = (const float*)d_in[15];
    const float* b_out       = (const float*)d_in[16];
    const float* cams_embeds = (const float*)d_in[17];
    const float* level_embeds= (const float*)d_in[18];
    const float* ln_g        = (const float*)d_in[19];
    const float* ln_b        = (const float*)d_in[20];
    const int*   img_h       = (const int*)d_in[21];
    const int*   img_w       = (const int*)d_in[22];

    // workspace layout (total 64,849,920 B = 61.9 MiB)
    char* ws = (char*)d_ws;
    float* coor  = (float*)(ws + 0);           //  6*6400*2 f32      =   307,200
    float* maskf = (float*)(ws + 307200);      //  6*6400 f32        =   153,600
    float* offs  = (float*)(ws + 460800);      //  6400*384 f32      = 9,830,400
    bf16*  attn  = (bf16*) (ws + 10291200);    //  6400*192 bf16     = 2,457,600
    bf16*  Wvp   = (bf16*) (ws + 12748800);    //  256*256 bf16      =   131,072
    float* slots = (float*)(ws + 12879872);    //  6400*256 f32      = 6,553,600
    bf16*  value = (bf16*) (ws + 19433472);    //  6*8*14784*32 bf16 = 45,416,448
    if (ws_size < 64849920u) return;

    k_proj   <<<150, 256, 0, stream>>>(means, cam2ego, intrins, post_rots, post_trans, img_h, img_w, coor, maskf);
    k_offattn<<<800, 256, 0, stream>>>(feature, W_off, b_off, W_attn, b_attn, offs, attn);
    k_pack   <<<32, 256, 0, stream>>>(W_val, Wvp);
    k_valproj<<<1386, 256, 0, stream>>>(feat0, feat1, feat2, cams_embeds, level_embeds, Wvp, b_val, value);
    k_msda   <<<1600, 256, 0, stream>>>(coor, offs, attn, value, maskf, slots);
    k_final  <<<800, 256, 0, stream>>>(slots, maskf, W_out, b_out, feature, ln_g, ln_b, (float*)d_out);
}

// Round 6
// 403.303 us; speedup vs baseline: 2.3957x; 1.0386x over previous
//
#include <hip/hip_runtime.h>
#include <hip/hip_bf16.h>

typedef __bf16 bf16;
typedef __attribute__((ext_vector_type(4))) float f32x4;
typedef __attribute__((ext_vector_type(8))) bf16 bf16x8;
typedef __attribute__((ext_vector_type(4))) bf16 bf16x4;

#define NCAMS 6
#define NQ 6400
#define CH 256
#define NH 8
#define NL 3
#define NP 8
#define S_TOT 14784   // 64*176 + 32*88 + 16*44

// ---------------------------------------------------------------- K1: projection
__global__ __launch_bounds__(256) void k_proj(
    const float* __restrict__ means, const float* __restrict__ cam2ego,
    const float* __restrict__ intrins, const float* __restrict__ post_rots,
    const float* __restrict__ post_trans, const int* __restrict__ img_h,
    const int* __restrict__ img_w, float* __restrict__ coor, float* __restrict__ maskf)
{
    int idx = blockIdx.x * 256 + threadIdx.x;
    if (idx >= NCAMS * NQ) return;
    int cam = idx / NQ, n = idx % NQ;
    float mx = means[n*3+0], my = means[n*3+1], mz = means[n*3+2];
    const float* M = cam2ego + cam*16;
    float R[3][3], t[3];
    #pragma unroll
    for (int r = 0; r < 3; r++) {
        #pragma unroll
        for (int c = 0; c < 3; c++) R[r][c] = M[r*4+c];
        t[r] = M[r*4+3];
    }
    float dx = mx - t[0], dy = my - t[1], dz = mz - t[2];
    float xc = R[0][0]*dx + R[1][0]*dy + R[2][0]*dz;
    float yc = R[0][1]*dx + R[1][1]*dy + R[2][1]*dz;
    float zc = R[0][2]*dx + R[1][2]*dy + R[2][2]*dz;
    const float* K = intrins + cam*9;
    float ix = K[0]*xc + K[1]*yc + K[2]*zc;
    float iy = K[3]*xc + K[4]*yc + K[5]*zc;
    float iz = K[6]*xc + K[7]*yc + K[8]*zc;
    float px = ix / (iz + 1e-4f), py = iy / (iz + 1e-4f), pz = iz;
    const float* P = post_rots + cam*9;
    const float* T = post_trans + cam*3;
    float vx = P[0]*px + P[1]*py + P[2]*pz + T[0];
    float vy = P[3]*px + P[4]*py + P[5]*pz + T[1];
    float vz = P[6]*px + P[7]*py + P[8]*pz + T[2];
    float cx = vx / (float)img_w[0];
    float cy = vy / (float)img_h[0];
    bool ok = (vz > 0.01f) && (cx > 0.f) && (cx < 1.f) && (cy > 0.f) && (cy < 1.f);
    coor[idx*2+0] = cx;
    coor[idx*2+1] = cy;
    maskf[idx] = ok ? 1.f : 0.f;
}

// ---------------------------------------------------------------- K2: offsets + attn (+softmax)
__global__ __launch_bounds__(256) void k_offattn(
    const float* __restrict__ feature, const float* __restrict__ W_off,
    const float* __restrict__ b_off, const float* __restrict__ W_attn,
    const float* __restrict__ b_attn, float* __restrict__ offs, bf16* __restrict__ attn_out)
{
    __shared__ float ft[256*8];    // [k][q]
    __shared__ float lg[8*192];    // attn logits [q][a]
    int t = threadIdx.x;
    int n0 = blockIdx.x * 8;
    #pragma unroll
    for (int q = 0; q < 8; q++) ft[t*8+q] = feature[(size_t)(n0+q)*CH + t];
    __syncthreads();

    float a0[8] = {}, a1[8] = {}, a2[8] = {};
    for (int k = 0; k < 256; k++) {
        float w0 = W_off[k*384 + t];
        float w1 = (t < 128) ? W_off[k*384 + 256 + t] : W_attn[k*192 + (t-128)];
        float w2 = (t < 64) ? W_attn[k*192 + 128 + t] : 0.f;
        const float* fk = &ft[k*8];
        #pragma unroll
        for (int q = 0; q < 8; q++) {
            float f = fk[q];
            a0[q] += f*w0; a1[q] += f*w1; a2[q] += f*w2;
        }
    }
    float b0 = b_off[t];
    #pragma unroll
    for (int q = 0; q < 8; q++) offs[(size_t)(n0+q)*384 + t] = a0[q] + b0;
    if (t < 128) {
        float b1 = b_off[256 + t];
        #pragma unroll
        for (int q = 0; q < 8; q++) offs[(size_t)(n0+q)*384 + 256 + t] = a1[q] + b1;
    } else {
        float b1 = b_attn[t-128];
        #pragma unroll
        for (int q = 0; q < 8; q++) lg[q*192 + (t-128)] = a1[q] + b1;
    }
    if (t < 64) {
        float b2 = b_attn[128 + t];
        #pragma unroll
        for (int q = 0; q < 8; q++) lg[q*192 + 128 + t] = a2[q] + b2;
    }
    __syncthreads();
    if (t < 64) {
        int q = t >> 3, h = t & 7;
        const float* L = &lg[q*192 + h*24];
        float m = -1e30f;
        #pragma unroll
        for (int j = 0; j < 24; j++) m = fmaxf(m, L[j]);
        float e[24]; float s = 0.f;
        #pragma unroll
        for (int j = 0; j < 24; j++) { e[j] = __expf(L[j] - m); s += e[j]; }
        float inv = 1.f / s;
        #pragma unroll
        for (int j = 0; j < 24; j++) attn_out[(size_t)(n0+q)*192 + h*24 + j] = (bf16)(e[j]*inv);
    }
}

// ---------------------------------------------------------------- K3a: pack W_val into B-fragment order (bf16)
__global__ __launch_bounds__(256) void k_pack(const float* __restrict__ W_val, bf16* __restrict__ Wvp)
{
    int flat = blockIdx.x * 256 + threadIdx.x;   // (kc*16+nf)*64 + lane
    int kc = flat >> 10;
    int rem = flat & 1023;
    int nf = rem >> 6;
    int lane = rem & 63;
    int q = lane >> 4;
    int col = nf*16 + (lane & 15);
    bf16x8 v;
    #pragma unroll
    for (int j = 0; j < 8; j++) v[j] = (bf16)W_val[(size_t)(kc*32 + q*8 + j)*256 + col];
    *reinterpret_cast<bf16x8*>(Wvp + (size_t)flat*8) = v;
}

// ---------------------------------------------------------------- K3: value projection GEMM (MFMA bf16)
// value layout: [cam][head][pos][32ch]  (bf16)
__global__ __launch_bounds__(256) void k_valproj(
    const float* __restrict__ f0, const float* __restrict__ f1, const float* __restrict__ f2,
    const float* __restrict__ cams_embeds, const float* __restrict__ level_embeds,
    const bf16* __restrict__ Wvp, const float* __restrict__ b_val, bf16* __restrict__ value)
{
    __shared__ alignas(16) bf16 A[64][48];   // [m][k], padded row 48
    int bi = blockIdx.x;
    int cam = bi / 231, mb = bi % 231;
    int lvl, local0, HW;
    const float* fp;
    if (mb < 176)      { lvl = 0; local0 = mb*64;        fp = f0; HW = 11264; }
    else if (mb < 220) { lvl = 1; local0 = (mb-176)*64;  fp = f1; HW = 2816;  }
    else               { lvl = 2; local0 = (mb-220)*64;  fp = f2; HW = 704;   }
    int pos0 = (lvl == 0 ? 0 : (lvl == 1 ? 11264 : 14080)) + local0;
    const float* featbase = fp + (size_t)cam*CH*HW + local0;

    int t = threadIdx.x;
    int lane = t & 63, w = t >> 6;
    int kk = t >> 3;            // 0..31 (channel within chunk)
    int m8 = (t & 7) * 8;       // m start
    int q = lane >> 4, r16 = lane & 15;

    f32x4 acc[4][4];
    #pragma unroll
    for (int i = 0; i < 4; i++)
        #pragma unroll
        for (int j = 0; j < 4; j++) acc[i][j] = (f32x4){0.f,0.f,0.f,0.f};

    for (int kc = 0; kc < 8; kc++) {
        __syncthreads();
        int kg = kc*32 + kk;
        float e = cams_embeds[cam*CH + kg] + level_embeds[lvl*CH + kg];
        f32x4 v0 = *reinterpret_cast<const f32x4*>(featbase + (size_t)kg*HW + m8);
        f32x4 v1 = *reinterpret_cast<const f32x4*>(featbase + (size_t)kg*HW + m8 + 4);
        #pragma unroll
        for (int i = 0; i < 4; i++) A[m8+i][kk]   = (bf16)(v0[i] + e);
        #pragma unroll
        for (int i = 0; i < 4; i++) A[m8+4+i][kk] = (bf16)(v1[i] + e);
        __syncthreads();

        bf16x8 bfr[4];
        #pragma unroll
        for (int nf = 0; nf < 4; nf++) {
            int nfg = w*4 + nf;
            bfr[nf] = *reinterpret_cast<const bf16x8*>(Wvp + ((size_t)(kc*16 + nfg)*64 + lane)*8);
        }
        #pragma unroll
        for (int mf = 0; mf < 4; mf++) {
            bf16x8 afr = *reinterpret_cast<const bf16x8*>(&A[mf*16 + r16][q*8]);
            #pragma unroll
            for (int nf = 0; nf < 4; nf++)
                acc[mf][nf] = __builtin_amdgcn_mfma_f32_16x16x32_bf16(afr, bfr[nf], acc[mf][nf], 0, 0, 0);
        }
    }
    // epilogue: D[row=(lane>>4)*4+r][col=lane&15]; write to [cam][head][pos][32]
    #pragma unroll
    for (int mf = 0; mf < 4; mf++) {
        #pragma unroll
        for (int nf = 0; nf < 4; nf++) {
            int c = w*64 + nf*16 + r16;
            int head = c >> 5, ch = c & 31;
            float bv = b_val[c];
            #pragma unroll
            for (int r = 0; r < 4; r++) {
                int srow = pos0 + mf*16 + q*4 + r;
                value[((size_t)(cam*NH + head)*S_TOT + srow)*32 + ch] = (bf16)(acc[mf][nf][r] + bv);
            }
        }
    }
}

// ---------------------------------------------------------------- K4: MSDA gather
// One wave per (query, head-pair): 25600 waves. Block = query, wave wv = heads wv*2..wv*2+1.
// Phase 1 (per cam, lanes 0..47): weights*attn (validity-zeroed) + corner byte offsets -> wave-private LDS.
// Phase 2 (per cam): lane = p*8+k, 6 (h,lvl) iters, uint2 loads, bf16 bit-unpack, fma.
// Final: xor-reduce over p, direct store (exclusive ownership, no atomics).
__global__ __launch_bounds__(256) void k_msda(
    const float* __restrict__ coor, const float* __restrict__ offs,
    const bf16* __restrict__ attn, const bf16* __restrict__ value,
    const float* __restrict__ maskf, float* __restrict__ slots)
{
    __shared__ f32x4 s_w[4][48];
    __shared__ int4  s_o[4][48];
    int wv = threadIdx.x >> 6;
    int lane = threadIdx.x & 63;
    int n = blockIdx.x;
    int h0 = wv * 2;                         // this wave's first head
    int p = lane >> 3, k = lane & 7;
    int kb = k * 8;                          // byte offset of this lane's 4 channels

    // hoist this wave's 48 sample params (reused by all cams)
    float oxr = 0.f, oyr = 0.f, awr = 0.f;
    int smm = h0*24 + lane;                  // global sample id for lane<48
    if (lane < 48) {
        float2 o2 = *reinterpret_cast<const float2*>(offs + (size_t)n*384 + smm*2);
        oxr = o2.x; oyr = o2.y;
        awr = (float)attn[(size_t)n*192 + smm];
    }

    f32x4 acc[2];
    acc[0] = (f32x4){0.f, 0.f, 0.f, 0.f};
    acc[1] = (f32x4){0.f, 0.f, 0.f, 0.f};

    const char* vbyte = (const char*)value;

    for (int cam = 0; cam < NCAMS; cam++) {
        if (maskf[cam*NQ + n] == 0.f) continue;
        float cx = coor[(cam*NQ + n)*2 + 0];
        float cy = coor[(cam*NQ + n)*2 + 1];

        if (lane < 48) {
            int hl = lane / 24;              // 0..1
            int r = lane - hl*24;
            int lvl = r >> 3;
            int h = h0 + hl;
            int wi   = (lvl == 0) ? 176 : ((lvl == 1) ? 88 : 44);
            int hi   = (lvl == 0) ? 64  : ((lvl == 1) ? 32 : 16);
            int base = (lvl == 0) ? 0   : ((lvl == 1) ? 11264 : 14080);
            float x = cx*(float)wi + oxr - 0.5f;
            float y = cy*(float)hi + oyr - 0.5f;
            float xf = floorf(x), yf = floorf(y);
            float tx = x - xf, ty = y - yf;
            float wm1x = (float)(wi-1), wm1y = (float)(hi-1);
            bool vx0 = (xf >= 0.f)      && (xf <= wm1x);
            bool vx1 = (xf+1.f >= 0.f)  && (xf+1.f <= wm1x);
            bool vy0 = (yf >= 0.f)      && (yf <= wm1y);
            bool vy1 = (yf+1.f >= 0.f)  && (yf+1.f <= wm1y);
            int x0 = (int)fminf(fmaxf(xf,      0.f), wm1x);
            int x1 = (int)fminf(fmaxf(xf+1.f,  0.f), wm1x);
            int y0 = (int)fminf(fmaxf(yf,      0.f), wm1y);
            int y1 = (int)fminf(fmaxf(yf+1.f,  0.f), wm1y);
            float w00 = (1.f-tx)*(1.f-ty)*awr * ((vx0 && vy0) ? 1.f : 0.f);
            float w10 = tx*(1.f-ty)*awr       * ((vx1 && vy0) ? 1.f : 0.f);
            float w01 = (1.f-tx)*ty*awr       * ((vx0 && vy1) ? 1.f : 0.f);
            float w11 = tx*ty*awr             * ((vx1 && vy1) ? 1.f : 0.f);
            int rowb = (cam*NH + h)*S_TOT + base;
            int r0 = rowb + y0*wi, r1 = rowb + y1*wi;
            s_w[wv][lane] = (f32x4){w00, w10, w01, w11};
            s_o[wv][lane] = make_int4((r0 + x0)*64, (r0 + x1)*64, (r1 + x0)*64, (r1 + x1)*64);
        }
        // wave-private LDS: per-wave DS ordering; no barrier needed

        #pragma unroll
        for (int hl = 0; hl < 2; hl++) {
            #pragma unroll
            for (int lvl = 0; lvl < 3; lvl++) {
                int mml = hl*24 + lvl*8 + p;
                f32x4 w4 = s_w[wv][mml];
                int4  o4 = s_o[wv][mml];
                uint2 d00 = *reinterpret_cast<const uint2*>(vbyte + (o4.x + kb));
                uint2 d10 = *reinterpret_cast<const uint2*>(vbyte + (o4.y + kb));
                uint2 d01 = *reinterpret_cast<const uint2*>(vbyte + (o4.z + kb));
                uint2 d11 = *reinterpret_cast<const uint2*>(vbyte + (o4.w + kb));
                acc[hl][0] = fmaf(__uint_as_float(d00.x << 16),          w4.x, acc[hl][0]);
                acc[hl][1] = fmaf(__uint_as_float(d00.x & 0xffff0000u),  w4.x, acc[hl][1]);
                acc[hl][2] = fmaf(__uint_as_float(d00.y << 16),          w4.x, acc[hl][2]);
                acc[hl][3] = fmaf(__uint_as_float(d00.y & 0xffff0000u),  w4.x, acc[hl][3]);
                acc[hl][0] = fmaf(__uint_as_float(d10.x << 16),          w4.y, acc[hl][0]);
                acc[hl][1] = fmaf(__uint_as_float(d10.x & 0xffff0000u),  w4.y, acc[hl][1]);
                acc[hl][2] = fmaf(__uint_as_float(d10.y << 16),          w4.y, acc[hl][2]);
                acc[hl][3] = fmaf(__uint_as_float(d10.y & 0xffff0000u),  w4.y, acc[hl][3]);
                acc[hl][0] = fmaf(__uint_as_float(d01.x << 16),          w4.z, acc[hl][0]);
                acc[hl][1] = fmaf(__uint_as_float(d01.x & 0xffff0000u),  w4.z, acc[hl][1]);
                acc[hl][2] = fmaf(__uint_as_float(d01.y << 16),          w4.z, acc[hl][2]);
                acc[hl][3] = fmaf(__uint_as_float(d01.y & 0xffff0000u),  w4.z, acc[hl][3]);
                acc[hl][0] = fmaf(__uint_as_float(d11.x << 16),          w4.w, acc[hl][0]);
                acc[hl][1] = fmaf(__uint_as_float(d11.x & 0xffff0000u),  w4.w, acc[hl][1]);
                acc[hl][2] = fmaf(__uint_as_float(d11.y << 16),          w4.w, acc[hl][2]);
                acc[hl][3] = fmaf(__uint_as_float(d11.y & 0xffff0000u),  w4.w, acc[hl][3]);
            }
        }
    }

    // reduce over p (8 lane-groups), lane group p==0 owns channels k*4..k*4+3
    #pragma unroll
    for (int hl = 0; hl < 2; hl++)
        #pragma unroll
        for (int i = 0; i < 4; i++) {
            acc[hl][i] += __shfl_xor(acc[hl][i], 8);
            acc[hl][i] += __shfl_xor(acc[hl][i], 16);
            acc[hl][i] += __shfl_xor(acc[hl][i], 32);
        }
    if (p == 0) {
        #pragma unroll
        for (int hl = 0; hl < 2; hl++)
            *reinterpret_cast<f32x4*>(slots + (size_t)n*CH + (h0+hl)*32 + k*4) = acc[hl];
    }
}

// ---------------------------------------------------------------- K6: mask-mean + out proj + residual + LN
__global__ __launch_bounds__(256) void k_final(
    const float* __restrict__ slots, const float* __restrict__ maskf,
    const float* __restrict__ W_out, const float* __restrict__ b_out,
    const float* __restrict__ feature, const float* __restrict__ ln_g,
    const float* __restrict__ ln_b, float* __restrict__ out)
{
    __shared__ float ft[256*8];   // slots [k][q]
    __shared__ float yb[8*256];   // y [q][c]
    __shared__ float mu_s[8], rs_s[8];
    int t = threadIdx.x;
    int n0 = blockIdx.x * 8;
    #pragma unroll
    for (int q = 0; q < 8; q++) {
        int n = n0 + q;
        float msum = 0.f;
        #pragma unroll
        for (int cam = 0; cam < NCAMS; cam++) msum += maskf[cam*NQ + n];
        ft[t*8+q] = slots[(size_t)n*CH + t] / fmaxf(msum, 1.f);
    }
    __syncthreads();
    float y[8] = {};
    for (int k = 0; k < 256; k++) {
        float wv = W_out[k*CH + t];
        const float* fk = &ft[k*8];
        #pragma unroll
        for (int q = 0; q < 8; q++) y[q] += fk[q]*wv;
    }
    float bo = b_out[t];
    #pragma unroll
    for (int q = 0; q < 8; q++) {
        y[q] += bo + feature[(size_t)(n0+q)*CH + t];
        yb[q*256 + t] = y[q];
    }
    __syncthreads();
    int lane = t & 63, w = t >> 6;
    int q = w*2 + (lane >> 5);
    int l32 = lane & 31;
    float s = 0.f, s2 = 0.f;
    #pragma unroll
    for (int c = l32; c < 256; c += 32) {
        float v = yb[q*256 + c];
        s += v; s2 += v*v;
    }
    #pragma unroll
    for (int off = 16; off > 0; off >>= 1) {
        s  += __shfl_xor(s, off);
        s2 += __shfl_xor(s2, off);
    }
    if (l32 == 0) {
        float mu = s / 256.f;
        float var = s2 / 256.f - mu*mu;
        mu_s[q] = mu;
        rs_s[q] = rsqrtf(var + 1e-5f);
    }
    __syncthreads();
    float g = ln_g[t], bb = ln_b[t];
    #pragma unroll
    for (int qq = 0; qq < 8; qq++) {
        float v = (yb[qq*256 + t] - mu_s[qq]) * rs_s[qq] * g + bb;
        out[(size_t)(n0+qq)*CH + t] = v;
    }
}

// ---------------------------------------------------------------- launch
extern "C" void kernel_launch(void* const* d_in, const int* in_sizes, int n_in,
                              void* d_out, int out_size, void* d_ws, size_t ws_size,
                              hipStream_t stream)
{
    const float* means       = (const float*)d_in[0];
    const float* feature     = (const float*)d_in[1];
    const float* feat0       = (const float*)d_in[2];
    const float* feat1       = (const float*)d_in[3];
    const float* feat2       = (const float*)d_in[4];
    const float* cam2ego     = (const float*)d_in[5];
    const float* intrins     = (const float*)d_in[6];
    const float* post_rots   = (const float*)d_in[7];
    const float* post_trans  = (const float*)d_in[8];
    const float* W_off       = (const float*)d_in[9];
    const float* b_off       = (const float*)d_in[10];
    const float* W_attn      = (const float*)d_in[11];
    const float* b_attn      = (const float*)d_in[12];
    const float* W_val       = (const float*)d_in[13];
    const float* b_val       = (const float*)d_in[14];
    const float* W_out       = (const float*)d_in[15];
    const float* b_out       = (const float*)d_in[16];
    const float* cams_embeds = (const float*)d_in[17];
    const float* level_embeds= (const float*)d_in[18];
    const float* ln_g        = (const float*)d_in[19];
    const float* ln_b        = (const float*)d_in[20];
    const int*   img_h       = (const int*)d_in[21];
    const int*   img_w       = (const int*)d_in[22];

    // workspace layout (total 64,849,920 B = 61.9 MiB)
    char* ws = (char*)d_ws;
    float* coor  = (float*)(ws + 0);           //  6*6400*2 f32      =   307,200
    float* maskf = (float*)(ws + 307200);      //  6*6400 f32        =   153,600
    float* offs  = (float*)(ws + 460800);      //  6400*384 f32      = 9,830,400
    bf16*  attn  = (bf16*) (ws + 10291200);    //  6400*192 bf16     = 2,457,600
    bf16*  Wvp   = (bf16*) (ws + 12748800);    //  256*256 bf16      =   131,072
    float* slots = (float*)(ws + 12879872);    //  6400*256 f32      = 6,553,600
    bf16*  value = (bf16*) (ws + 19433472);    //  6*8*14784*32 bf16 = 45,416,448
    if (ws_size < 64849920u) return;

    k_proj   <<<150, 256, 0, stream>>>(means, cam2ego, intrins, post_rots, post_trans, img_h, img_w, coor, maskf);
    k_offattn<<<800, 256, 0, stream>>>(feature, W_off, b_off, W_attn, b_attn, offs, attn);
    k_pack   <<<32, 256, 0, stream>>>(W_val, Wvp);
    k_valproj<<<1386, 256, 0, stream>>>(feat0, feat1, feat2, cams_embeds, level_embeds, Wvp, b_val, value);
    k_msda   <<<6400, 256, 0, stream>>>(coor, offs, attn, value, maskf, slots);
    k_final  <<<800, 256, 0, stream>>>(slots, maskf, W_out, b_out, feature, ln_g, ln_b, (float*)d_out);
}

// Round 8
// 392.091 us; speedup vs baseline: 2.4642x; 1.0286x over previous
//
#include <hip/hip_runtime.h>
#include <hip/hip_bf16.h>

typedef __bf16 bf16;
typedef __attribute__((ext_vector_type(4))) float f32x4;
typedef __attribute__((ext_vector_type(8))) bf16 bf16x8;
typedef __attribute__((ext_vector_type(4))) bf16 bf16x4;
typedef __attribute__((ext_vector_type(2))) bf16 bf16x2;

#define NCAMS 6
#define NQ 6400
#define CH 256
#define NH 8
#define NL 3
#define NP 8
#define S_TOT 14784   // 64*176 + 32*88 + 16*44

#if __has_builtin(__builtin_amdgcn_fdot2_f32_bf16) && __has_builtin(__builtin_amdgcn_perm)
#define MSDA_DOT2 1
#else
#define MSDA_DOT2 0
#endif

// ---------------------------------------------------------------- K1: projection
__global__ __launch_bounds__(256) void k_proj(
    const float* __restrict__ means, const float* __restrict__ cam2ego,
    const float* __restrict__ intrins, const float* __restrict__ post_rots,
    const float* __restrict__ post_trans, const int* __restrict__ img_h,
    const int* __restrict__ img_w, float* __restrict__ coor, float* __restrict__ maskf)
{
    int idx = blockIdx.x * 256 + threadIdx.x;
    if (idx >= NCAMS * NQ) return;
    int cam = idx / NQ, n = idx % NQ;
    float mx = means[n*3+0], my = means[n*3+1], mz = means[n*3+2];
    const float* M = cam2ego + cam*16;
    float R[3][3], t[3];
    #pragma unroll
    for (int r = 0; r < 3; r++) {
        #pragma unroll
        for (int c = 0; c < 3; c++) R[r][c] = M[r*4+c];
        t[r] = M[r*4+3];
    }
    float dx = mx - t[0], dy = my - t[1], dz = mz - t[2];
    float xc = R[0][0]*dx + R[1][0]*dy + R[2][0]*dz;
    float yc = R[0][1]*dx + R[1][1]*dy + R[2][1]*dz;
    float zc = R[0][2]*dx + R[1][2]*dy + R[2][2]*dz;
    const float* K = intrins + cam*9;
    float ix = K[0]*xc + K[1]*yc + K[2]*zc;
    float iy = K[3]*xc + K[4]*yc + K[5]*zc;
    float iz = K[6]*xc + K[7]*yc + K[8]*zc;
    float px = ix / (iz + 1e-4f), py = iy / (iz + 1e-4f), pz = iz;
    const float* P = post_rots + cam*9;
    const float* T = post_trans + cam*3;
    float vx = P[0]*px + P[1]*py + P[2]*pz + T[0];
    float vy = P[3]*px + P[4]*py + P[5]*pz + T[1];
    float vz = P[6]*px + P[7]*py + P[8]*pz + T[2];
    float cx = vx / (float)img_w[0];
    float cy = vy / (float)img_h[0];
    bool ok = (vz > 0.01f) && (cx > 0.f) && (cx < 1.f) && (cy > 0.f) && (cy < 1.f);
    coor[idx*2+0] = cx;
    coor[idx*2+1] = cy;
    maskf[idx] = ok ? 1.f : 0.f;
}

// ---------------------------------------------------------------- K2: offsets + attn (+softmax)
__global__ __launch_bounds__(256) void k_offattn(
    const float* __restrict__ feature, const float* __restrict__ W_off,
    const float* __restrict__ b_off, const float* __restrict__ W_attn,
    const float* __restrict__ b_attn, float* __restrict__ offs, bf16* __restrict__ attn_out)
{
    __shared__ float ft[256*8];    // [k][q]
    __shared__ float lg[8*192];    // attn logits [q][a]
    int t = threadIdx.x;
    int n0 = blockIdx.x * 8;
    #pragma unroll
    for (int q = 0; q < 8; q++) ft[t*8+q] = feature[(size_t)(n0+q)*CH + t];
    __syncthreads();

    float a0[8] = {}, a1[8] = {}, a2[8] = {};
    for (int k = 0; k < 256; k++) {
        float w0 = W_off[k*384 + t];
        float w1 = (t < 128) ? W_off[k*384 + 256 + t] : W_attn[k*192 + (t-128)];
        float w2 = (t < 64) ? W_attn[k*192 + 128 + t] : 0.f;
        const float* fk = &ft[k*8];
        #pragma unroll
        for (int q = 0; q < 8; q++) {
            float f = fk[q];
            a0[q] += f*w0; a1[q] += f*w1; a2[q] += f*w2;
        }
    }
    float b0 = b_off[t];
    #pragma unroll
    for (int q = 0; q < 8; q++) offs[(size_t)(n0+q)*384 + t] = a0[q] + b0;
    if (t < 128) {
        float b1 = b_off[256 + t];
        #pragma unroll
        for (int q = 0; q < 8; q++) offs[(size_t)(n0+q)*384 + 256 + t] = a1[q] + b1;
    } else {
        float b1 = b_attn[t-128];
        #pragma unroll
        for (int q = 0; q < 8; q++) lg[q*192 + (t-128)] = a1[q] + b1;
    }
    if (t < 64) {
        float b2 = b_attn[128 + t];
        #pragma unroll
        for (int q = 0; q < 8; q++) lg[q*192 + 128 + t] = a2[q] + b2;
    }
    __syncthreads();
    if (t < 64) {
        int q = t >> 3, h = t & 7;
        const float* L = &lg[q*192 + h*24];
        float m = -1e30f;
        #pragma unroll
        for (int j = 0; j < 24; j++) m = fmaxf(m, L[j]);
        float e[24]; float s = 0.f;
        #pragma unroll
        for (int j = 0; j < 24; j++) { e[j] = __expf(L[j] - m); s += e[j]; }
        float inv = 1.f / s;
        #pragma unroll
        for (int j = 0; j < 24; j++) attn_out[(size_t)(n0+q)*192 + h*24 + j] = (bf16)(e[j]*inv);
    }
}

// ---------------------------------------------------------------- K3a: pack W_val into B-fragment order (bf16)
__global__ __launch_bounds__(256) void k_pack(const float* __restrict__ W_val, bf16* __restrict__ Wvp)
{
    int flat = blockIdx.x * 256 + threadIdx.x;   // (kc*16+nf)*64 + lane
    int kc = flat >> 10;
    int rem = flat & 1023;
    int nf = rem >> 6;
    int lane = rem & 63;
    int q = lane >> 4;
    int col = nf*16 + (lane & 15);
    bf16x8 v;
    #pragma unroll
    for (int j = 0; j < 8; j++) v[j] = (bf16)W_val[(size_t)(kc*32 + q*8 + j)*256 + col];
    *reinterpret_cast<bf16x8*>(Wvp + (size_t)flat*8) = v;
}

// ---------------------------------------------------------------- K3: value projection GEMM (MFMA bf16)
// value layout: [cam][head][pos][32ch]  (bf16)
__global__ __launch_bounds__(256) void k_valproj(
    const float* __restrict__ f0, const float* __restrict__ f1, const float* __restrict__ f2,
    const float* __restrict__ cams_embeds, const float* __restrict__ level_embeds,
    const bf16* __restrict__ Wvp, const float* __restrict__ b_val, bf16* __restrict__ value)
{
    __shared__ alignas(16) bf16 A[64][48];    // [m][k], padded row 48 (6144 B)
    __shared__ alignas(16) bf16 Cst[16][256]; // epilogue staging stripe (8192 B)
    int bi = blockIdx.x;
    int cam = bi / 231, mb = bi % 231;
    int lvl, local0, HW;
    const float* fp;
    if (mb < 176)      { lvl = 0; local0 = mb*64;        fp = f0; HW = 11264; }
    else if (mb < 220) { lvl = 1; local0 = (mb-176)*64;  fp = f1; HW = 2816;  }
    else               { lvl = 2; local0 = (mb-220)*64;  fp = f2; HW = 704;   }
    int pos0 = (lvl == 0 ? 0 : (lvl == 1 ? 11264 : 14080)) + local0;
    const float* featbase = fp + (size_t)cam*CH*HW + local0;

    int t = threadIdx.x;
    int lane = t & 63, w = t >> 6;
    int kk = t >> 3;            // 0..31 (channel within chunk)
    int m8 = (t & 7) * 8;       // m start
    int q = lane >> 4, r16 = lane & 15;

    f32x4 acc[4][4];
    #pragma unroll
    for (int i = 0; i < 4; i++)
        #pragma unroll
        for (int j = 0; j < 4; j++) acc[i][j] = (f32x4){0.f,0.f,0.f,0.f};

    for (int kc = 0; kc < 8; kc++) {
        __syncthreads();
        int kg = kc*32 + kk;
        float e = cams_embeds[cam*CH + kg] + level_embeds[lvl*CH + kg];
        f32x4 v0 = *reinterpret_cast<const f32x4*>(featbase + (size_t)kg*HW + m8);
        f32x4 v1 = *reinterpret_cast<const f32x4*>(featbase + (size_t)kg*HW + m8 + 4);
        #pragma unroll
        for (int i = 0; i < 4; i++) A[m8+i][kk]   = (bf16)(v0[i] + e);
        #pragma unroll
        for (int i = 0; i < 4; i++) A[m8+4+i][kk] = (bf16)(v1[i] + e);
        __syncthreads();

        bf16x8 bfr[4];
        #pragma unroll
        for (int nf = 0; nf < 4; nf++) {
            int nfg = w*4 + nf;
            bfr[nf] = *reinterpret_cast<const bf16x8*>(Wvp + ((size_t)(kc*16 + nfg)*64 + lane)*8);
        }
        #pragma unroll
        for (int mf = 0; mf < 4; mf++) {
            bf16x8 afr = *reinterpret_cast<const bf16x8*>(&A[mf*16 + r16][q*8]);
            #pragma unroll
            for (int nf = 0; nf < 4; nf++)
                acc[mf][nf] = __builtin_amdgcn_mfma_f32_16x16x32_bf16(afr, bfr[nf], acc[mf][nf], 0, 0, 0);
        }
    }
    // epilogue, per 16-row stripe: D[row=q*4+r][col=w*64+nf*16+r16] -> LDS -> coalesced 16B stores
    int orow = t >> 4;                // 0..15
    int ocol = (t & 15) * 16;         // 0..240 step 16 (within one head: 16 | 32)
    int ohead = ocol >> 5, och = ocol & 31;
    #pragma unroll
    for (int mf = 0; mf < 4; mf++) {
        __syncthreads();              // previous stripe fully read
        #pragma unroll
        for (int nf = 0; nf < 4; nf++) {
            int c = w*64 + nf*16 + r16;
            float bv = b_val[c];
            #pragma unroll
            for (int r = 0; r < 4; r++)
                Cst[q*4 + r][c] = (bf16)(acc[mf][nf][r] + bv);
        }
        __syncthreads();
        int srow = pos0 + mf*16 + orow;
        bf16* dst = value + ((size_t)(cam*NH + ohead)*S_TOT + srow)*32 + och;
        const f32x4* src = reinterpret_cast<const f32x4*>(&Cst[orow][ocol]);
        f32x4 x0 = src[0], x1 = src[1];
        reinterpret_cast<f32x4*>(dst)[0] = x0;
        reinterpret_cast<f32x4*>(dst)[1] = x1;
    }
}

// ---------------------------------------------------------------- K4: MSDA gather
// One wave per (query, head-pair): 25600 waves. Block = query, wave wv = heads wv*2..wv*2+1.
// Phase 1 (per cam, lanes 0..47): attn*validity-premultiplied bilinear weights (packed bf16x2
//   pairs for dot2 path) + corner byte offsets -> wave-private LDS.
// Phase 2 (per cam): lane = p*8+k, 6 (h,lvl) iters; v_perm pairs corners, v_dot2_f32_bf16
//   accumulates 2 MACs/inst (fallback: bit-unpack + fmaf).
// Final: xor-reduce over p, direct store (exclusive ownership, no atomics).
__global__ __launch_bounds__(256) void k_msda(
    const float* __restrict__ coor, const float* __restrict__ offs,
    const bf16* __restrict__ attn, const bf16* __restrict__ value,
    const float* __restrict__ maskf, float* __restrict__ slots)
{
#if MSDA_DOT2
    __shared__ uint2 s_w[4][48];
#else
    __shared__ f32x4 s_w[4][48];
#endif
    __shared__ int4  s_o[4][48];
    int wv = threadIdx.x >> 6;
    int lane = threadIdx.x & 63;
    int n = blockIdx.x;
    int h0 = wv * 2;                         // this wave's first head
    int p = lane >> 3, k = lane & 7;
    int kb = k * 8;                          // byte offset of this lane's 4 channels

    // hoist this wave's 48 sample params (reused by all cams)
    float oxr = 0.f, oyr = 0.f, awr = 0.f;
    int smm = h0*24 + lane;                  // global sample id for lane<48
    if (lane < 48) {
        float2 o2 = *reinterpret_cast<const float2*>(offs + (size_t)n*384 + smm*2);
        oxr = o2.x; oyr = o2.y;
        awr = (float)attn[(size_t)n*192 + smm];
    }

    f32x4 acc[2];
    acc[0] = (f32x4){0.f, 0.f, 0.f, 0.f};
    acc[1] = (f32x4){0.f, 0.f, 0.f, 0.f};

    const char* vbyte = (const char*)value;

    for (int cam = 0; cam < NCAMS; cam++) {
        if (maskf[cam*NQ + n] == 0.f) continue;
        float cx = coor[(cam*NQ + n)*2 + 0];
        float cy = coor[(cam*NQ + n)*2 + 1];

        if (lane < 48) {
            int hl = lane / 24;              // 0..1
            int r = lane - hl*24;
            int lvl = r >> 3;
            int h = h0 + hl;
            int wi   = (lvl == 0) ? 176 : ((lvl == 1) ? 88 : 44);
            int hi   = (lvl == 0) ? 64  : ((lvl == 1) ? 32 : 16);
            int base = (lvl == 0) ? 0   : ((lvl == 1) ? 11264 : 14080);
            float x = cx*(float)wi + oxr - 0.5f;
            float y = cy*(float)hi + oyr - 0.5f;
            float xf = floorf(x), yf = floorf(y);
            float tx = x - xf, ty = y - yf;
            float wm1x = (float)(wi-1), wm1y = (float)(hi-1);
            bool vx0 = (xf >= 0.f)      && (xf <= wm1x);
            bool vx1 = (xf+1.f >= 0.f)  && (xf+1.f <= wm1x);
            bool vy0 = (yf >= 0.f)      && (yf <= wm1y);
            bool vy1 = (yf+1.f >= 0.f)  && (yf+1.f <= wm1y);
            int x0 = (int)fminf(fmaxf(xf,      0.f), wm1x);
            int x1 = (int)fminf(fmaxf(xf+1.f,  0.f), wm1x);
            int y0 = (int)fminf(fmaxf(yf,      0.f), wm1y);
            int y1 = (int)fminf(fmaxf(yf+1.f,  0.f), wm1y);
            float w00 = (1.f-tx)*(1.f-ty)*awr * ((vx0 && vy0) ? 1.f : 0.f);
            float w10 = tx*(1.f-ty)*awr       * ((vx1 && vy0) ? 1.f : 0.f);
            float w01 = (1.f-tx)*ty*awr       * ((vx0 && vy1) ? 1.f : 0.f);
            float w11 = tx*ty*awr             * ((vx1 && vy1) ? 1.f : 0.f);
            int rowb = (cam*NH + h)*S_TOT + base;
            int r0 = rowb + y0*wi, r1 = rowb + y1*wi;
#if MSDA_DOT2
            bf16x2 wa; wa[0] = (bf16)w00; wa[1] = (bf16)w10;
            bf16x2 wb; wb[0] = (bf16)w01; wb[1] = (bf16)w11;
            s_w[wv][lane] = make_uint2(__builtin_bit_cast(unsigned, wa),
                                       __builtin_bit_cast(unsigned, wb));
#else
            s_w[wv][lane] = (f32x4){w00, w10, w01, w11};
#endif
            s_o[wv][lane] = make_int4((r0 + x0)*64, (r0 + x1)*64, (r1 + x0)*64, (r1 + x1)*64);
        }
        // wave-private LDS: per-wave DS ordering; no barrier needed

        #pragma unroll
        for (int hl = 0; hl < 2; hl++) {
            #pragma unroll
            for (int lvl = 0; lvl < 3; lvl++) {
                int mml = hl*24 + lvl*8 + p;
                int4  o4 = s_o[wv][mml];
#if MSDA_DOT2
                uint2 wp = s_w[wv][mml];
                bf16x2 wa = __builtin_bit_cast(bf16x2, wp.x);
                bf16x2 wb = __builtin_bit_cast(bf16x2, wp.y);
                uint2 d00 = *reinterpret_cast<const uint2*>(vbyte + (o4.x + kb));
                uint2 d10 = *reinterpret_cast<const uint2*>(vbyte + (o4.y + kb));
                uint2 d01 = *reinterpret_cast<const uint2*>(vbyte + (o4.z + kb));
                uint2 d11 = *reinterpret_cast<const uint2*>(vbyte + (o4.w + kb));
                // pair {v(00)ch, v(10)ch}: low16 from d00 (sel bytes 0,1 = S1), high16 from d10 (sel 4,5 = S0)
                unsigned a0p = __builtin_amdgcn_perm(d10.x, d00.x, 0x05040100u);
                unsigned a1p = __builtin_amdgcn_perm(d10.x, d00.x, 0x07060302u);
                unsigned a2p = __builtin_amdgcn_perm(d10.y, d00.y, 0x05040100u);
                unsigned a3p = __builtin_amdgcn_perm(d10.y, d00.y, 0x07060302u);
                unsigned b0p = __builtin_amdgcn_perm(d11.x, d01.x, 0x05040100u);
                unsigned b1p = __builtin_amdgcn_perm(d11.x, d01.x, 0x07060302u);
                unsigned b2p = __builtin_amdgcn_perm(d11.y, d01.y, 0x05040100u);
                unsigned b3p = __builtin_amdgcn_perm(d11.y, d01.y, 0x07060302u);
                acc[hl][0] = __builtin_amdgcn_fdot2_f32_bf16(__builtin_bit_cast(bf16x2, a0p), wa, acc[hl][0], false);
                acc[hl][1] = __builtin_amdgcn_fdot2_f32_bf16(__builtin_bit_cast(bf16x2, a1p), wa, acc[hl][1], false);
                acc[hl][2] = __builtin_amdgcn_fdot2_f32_bf16(__builtin_bit_cast(bf16x2, a2p), wa, acc[hl][2], false);
                acc[hl][3] = __builtin_amdgcn_fdot2_f32_bf16(__builtin_bit_cast(bf16x2, a3p), wa, acc[hl][3], false);
                acc[hl][0] = __builtin_amdgcn_fdot2_f32_bf16(__builtin_bit_cast(bf16x2, b0p), wb, acc[hl][0], false);
                acc[hl][1] = __builtin_amdgcn_fdot2_f32_bf16(__builtin_bit_cast(bf16x2, b1p), wb, acc[hl][1], false);
                acc[hl][2] = __builtin_amdgcn_fdot2_f32_bf16(__builtin_bit_cast(bf16x2, b2p), wb, acc[hl][2], false);
                acc[hl][3] = __builtin_amdgcn_fdot2_f32_bf16(__builtin_bit_cast(bf16x2, b3p), wb, acc[hl][3], false);
#else
                f32x4 w4 = s_w[wv][mml];
                uint2 d00 = *reinterpret_cast<const uint2*>(vbyte + (o4.x + kb));
                uint2 d10 = *reinterpret_cast<const uint2*>(vbyte + (o4.y + kb));
                uint2 d01 = *reinterpret_cast<const uint2*>(vbyte + (o4.z + kb));
                uint2 d11 = *reinterpret_cast<const uint2*>(vbyte + (o4.w + kb));
                acc[hl][0] = fmaf(__uint_as_float(d00.x << 16),          w4.x, acc[hl][0]);
                acc[hl][1] = fmaf(__uint_as_float(d00.x & 0xffff0000u),  w4.x, acc[hl][1]);
                acc[hl][2] = fmaf(__uint_as_float(d00.y << 16),          w4.x, acc[hl][2]);
                acc[hl][3] = fmaf(__uint_as_float(d00.y & 0xffff0000u),  w4.x, acc[hl][3]);
                acc[hl][0] = fmaf(__uint_as_float(d10.x << 16),          w4.y, acc[hl][0]);
                acc[hl][1] = fmaf(__uint_as_float(d10.x & 0xffff0000u),  w4.y, acc[hl][1]);
                acc[hl][2] = fmaf(__uint_as_float(d10.y << 16),          w4.y, acc[hl][2]);
                acc[hl][3] = fmaf(__uint_as_float(d10.y & 0xffff0000u),  w4.y, acc[hl][3]);
                acc[hl][0] = fmaf(__uint_as_float(d01.x << 16),          w4.z, acc[hl][0]);
                acc[hl][1] = fmaf(__uint_as_float(d01.x & 0xffff0000u),  w4.z, acc[hl][1]);
                acc[hl][2] = fmaf(__uint_as_float(d01.y << 16),          w4.z, acc[hl][2]);
                acc[hl][3] = fmaf(__uint_as_float(d01.y & 0xffff0000u),  w4.z, acc[hl][3]);
                acc[hl][0] = fmaf(__uint_as_float(d11.x << 16),          w4.w, acc[hl][0]);
                acc[hl][1] = fmaf(__uint_as_float(d11.x & 0xffff0000u),  w4.w, acc[hl][1]);
                acc[hl][2] = fmaf(__uint_as_float(d11.y << 16),          w4.w, acc[hl][2]);
                acc[hl][3] = fmaf(__uint_as_float(d11.y & 0xffff0000u),  w4.w, acc[hl][3]);
#endif
            }
        }
    }

    // reduce over p (8 lane-groups), lane group p==0 owns channels k*4..k*4+3
    #pragma unroll
    for (int hl = 0; hl < 2; hl++)
        #pragma unroll
        for (int i = 0; i < 4; i++) {
            acc[hl][i] += __shfl_xor(acc[hl][i], 8);
            acc[hl][i] += __shfl_xor(acc[hl][i], 16);
            acc[hl][i] += __shfl_xor(acc[hl][i], 32);
        }
    if (p == 0) {
        #pragma unroll
        for (int hl = 0; hl < 2; hl++)
            *reinterpret_cast<f32x4*>(slots + (size_t)n*CH + (h0+hl)*32 + k*4) = acc[hl];
    }
}

// ---------------------------------------------------------------- K6: mask-mean + out proj + residual + LN
__global__ __launch_bounds__(256) void k_final(
    const float* __restrict__ slots, const float* __restrict__ maskf,
    const float* __restrict__ W_out, const float* __restrict__ b_out,
    const float* __restrict__ feature, const float* __restrict__ ln_g,
    const float* __restrict__ ln_b, float* __restrict__ out)
{
    __shared__ float ft[256*8];   // slots [k][q]
    __shared__ float yb[8*256];   // y [q][c]
    __shared__ float mu_s[8], rs_s[8];
    int t = threadIdx.x;
    int n0 = blockIdx.x * 8;
    #pragma unroll
    for (int q = 0; q < 8; q++) {
        int n = n0 + q;
        float msum = 0.f;
        #pragma unroll
        for (int cam = 0; cam < NCAMS; cam++) msum += maskf[cam*NQ + n];
        ft[t*8+q] = slots[(size_t)n*CH + t] / fmaxf(msum, 1.f);
    }
    __syncthreads();
    float y[8] = {};
    for (int k = 0; k < 256; k++) {
        float wv = W_out[k*CH + t];
        const float* fk = &ft[k*8];
        #pragma unroll
        for (int q = 0; q < 8; q++) y[q] += fk[q]*wv;
    }
    float bo = b_out[t];
    #pragma unroll
    for (int q = 0; q < 8; q++) {
        y[q] += bo + feature[(size_t)(n0+q)*CH + t];
        yb[q*256 + t] = y[q];
    }
    __syncthreads();
    int lane = t & 63, w = t >> 6;
    int q = w*2 + (lane >> 5);
    int l32 = lane & 31;
    float s = 0.f, s2 = 0.f;
    #pragma unroll
    for (int c = l32; c < 256; c += 32) {
        float v = yb[q*256 + c];
        s += v; s2 += v*v;
    }
    #pragma unroll
    for (int off = 16; off > 0; off >>= 1) {
        s  += __shfl_xor(s, off);
        s2 += __shfl_xor(s2, off);
    }
    if (l32 == 0) {
        float mu = s / 256.f;
        float var = s2 / 256.f - mu*mu;
        mu_s[q] = mu;
        rs_s[q] = rsqrtf(var + 1e-5f);
    }
    __syncthreads();
    float g = ln_g[t], bb = ln_b[t];
    #pragma unroll
    for (int qq = 0; qq < 8; qq++) {
        float v = (yb[qq*256 + t] - mu_s[qq]) * rs_s[qq] * g + bb;
        out[(size_t)(n0+qq)*CH + t] = v;
    }
}

// ---------------------------------------------------------------- launch
extern "C" void kernel_launch(void* const* d_in, const int* in_sizes, int n_in,
                              void* d_out, int out_size, void* d_ws, size_t ws_size,
                              hipStream_t stream)
{
    const float* means       = (const float*)d_in[0];
    const float* feature     = (const float*)d_in[1];
    const float* feat0       = (const float*)d_in[2];
    const float* feat1       = (const float*)d_in[3];
    const float* feat2       = (const float*)d_in[4];
    const float* cam2ego     = (const float*)d_in[5];
    const float* intrins     = (const float*)d_in[6];
    const float* post_rots   = (const float*)d_in[7];
    const float* post_trans  = (const float*)d_in[8];
    const float* W_off       = (const float*)d_in[9];
    const float* b_off       = (const float*)d_in[10];
    const float* W_attn      = (const float*)d_in[11];
    const float* b_attn      = (const float*)d_in[12];
    const float* W_val       = (const float*)d_in[13];
    const float* b_val       = (const float*)d_in[14];
    const float* W_out       = (const float*)d_in[15];
    const float* b_out       = (const float*)d_in[16];
    const float* cams_embeds = (const float*)d_in[17];
    const float* level_embeds= (const float*)d_in[18];
    const float* ln_g        = (const float*)d_in[19];
    const float* ln_b        = (const float*)d_in[20];
    const int*   img_h       = (const int*)d_in[21];
    const int*   img_w       = (const int*)d_in[22];

    // workspace layout (total 64,849,920 B = 61.9 MiB)
    char* ws = (char*)d_ws;
    float* coor  = (float*)(ws + 0);           //  6*6400*2 f32      =   307,200
    float* maskf = (float*)(ws + 307200);      //  6*6400 f32        =   153,600
    float* offs  = (float*)(ws + 460800);      //  6400*384 f32      = 9,830,400
    bf16*  attn  = (bf16*) (ws + 10291200);    //  6400*192 bf16     = 2,457,600
    bf16*  Wvp   = (bf16*) (ws + 12748800);    //  256*256 bf16      =   131,072
    float* slots = (float*)(ws + 12879872);    //  6400*256 f32      = 6,553,600
    bf16*  value = (bf16*) (ws + 19433472);    //  6*8*14784*32 bf16 = 45,416,448
    if (ws_size < 64849920u) return;

    k_proj   <<<150, 256, 0, stream>>>(means, cam2ego, intrins, post_rots, post_trans, img_h, img_w, coor, maskf);
    k_offattn<<<800, 256, 0, stream>>>(feature, W_off, b_off, W_attn, b_attn, offs, attn);
    k_pack   <<<32, 256, 0, stream>>>(W_val, Wvp);
    k_valproj<<<1386, 256, 0, stream>>>(feat0, feat1, feat2, cams_embeds, level_embeds, Wvp, b_val, value);
    k_msda   <<<6400, 256, 0, stream>>>(coor, offs, attn, value, maskf, slots);
    k_final  <<<800, 256, 0, stream>>>(slots, maskf, W_out, b_out, feature, ln_g, ln_b, (float*)d_out);
}

// Round 9
// 320.643 us; speedup vs baseline: 3.0133x; 1.2228x over previous
//
#include <hip/hip_runtime.h>
#include <hip/hip_bf16.h>

typedef __bf16 bf16;
typedef __attribute__((ext_vector_type(4))) float f32x4;
typedef __attribute__((ext_vector_type(8))) bf16 bf16x8;
typedef __attribute__((ext_vector_type(2))) bf16 bf16x2;

#define NCAMS 6
#define NQ 6400
#define CH 256
#define NH 8
#define NL 3
#define NP 8
#define S_TOT 14784   // 64*176 + 32*88 + 16*44

#if __has_builtin(__builtin_amdgcn_fdot2_f32_bf16) && __has_builtin(__builtin_amdgcn_perm)
#define MSDA_DOT2 1
#else
#define MSDA_DOT2 0
#endif

// ---------------------------------------------------------------- K1: prep = projection + weight packs
// blocks 0..149: projection; blocks 150..285: pack Wvp (8192) / Woap (18432) / Wop (8192)
__global__ __launch_bounds__(256) void k_prep(
    const float* __restrict__ means, const float* __restrict__ cam2ego,
    const float* __restrict__ intrins, const float* __restrict__ post_rots,
    const float* __restrict__ post_trans, const int* __restrict__ img_h,
    const int* __restrict__ img_w,
    const float* __restrict__ W_val, const float* __restrict__ W_off,
    const float* __restrict__ W_attn, const float* __restrict__ W_out,
    float* __restrict__ coor, float* __restrict__ maskf,
    bf16* __restrict__ Wvp, bf16* __restrict__ Woap, bf16* __restrict__ Wop)
{
    int bid = blockIdx.x;
    if (bid < 150) {
        int idx = bid * 256 + threadIdx.x;
        if (idx >= NCAMS * NQ) return;
        int cam = idx / NQ, n = idx % NQ;
        float mx = means[n*3+0], my = means[n*3+1], mz = means[n*3+2];
        const float* M = cam2ego + cam*16;
        float R[3][3], t[3];
        #pragma unroll
        for (int r = 0; r < 3; r++) {
            #pragma unroll
            for (int c = 0; c < 3; c++) R[r][c] = M[r*4+c];
            t[r] = M[r*4+3];
        }
        float dx = mx - t[0], dy = my - t[1], dz = mz - t[2];
        float xc = R[0][0]*dx + R[1][0]*dy + R[2][0]*dz;
        float yc = R[0][1]*dx + R[1][1]*dy + R[2][1]*dz;
        float zc = R[0][2]*dx + R[1][2]*dy + R[2][2]*dz;
        const float* K = intrins + cam*9;
        float ix = K[0]*xc + K[1]*yc + K[2]*zc;
        float iy = K[3]*xc + K[4]*yc + K[5]*zc;
        float iz = K[6]*xc + K[7]*yc + K[8]*zc;
        float px = ix / (iz + 1e-4f), py = iy / (iz + 1e-4f), pz = iz;
        const float* P = post_rots + cam*9;
        const float* T = post_trans + cam*3;
        float vx = P[0]*px + P[1]*py + P[2]*pz + T[0];
        float vy = P[3]*px + P[4]*py + P[5]*pz + T[1];
        float vz = P[6]*px + P[7]*py + P[8]*pz + T[2];
        float cx = vx / (float)img_w[0];
        float cy = vy / (float)img_h[0];
        bool ok = (vz > 0.01f) && (cx > 0.f) && (cx < 1.f) && (cy > 0.f) && (cy < 1.f);
        coor[idx*2+0] = cx;
        coor[idx*2+1] = cy;
        maskf[idx] = ok ? 1.f : 0.f;
        return;
    }
    int flat = (bid - 150) * 256 + threadIdx.x;
    if (flat < 8192) {
        // Wvp: (kc*16+nf)*64+lane <- W_val[kc*32+q*8+j][nf*16+l15]
        int kc = flat >> 10, rem = flat & 1023;
        int nf = rem >> 6, lane = rem & 63;
        int q = lane >> 4, col = nf*16 + (lane & 15);
        bf16x8 v;
        #pragma unroll
        for (int j = 0; j < 8; j++) v[j] = (bf16)W_val[(size_t)(kc*32 + q*8 + j)*256 + col];
        *reinterpret_cast<bf16x8*>(Wvp + (size_t)flat*8) = v;
    } else if (flat < 26624) {
        // Woap: 576 logical cols = [W_off 0..383 | W_attn 384..575]
        int f2 = flat - 8192;
        int kc = f2 / (36*64), rem = f2 % (36*64);
        int nf = rem >> 6, lane = rem & 63;
        int q = lane >> 4, col = nf*16 + (lane & 15);
        bf16x8 v;
        #pragma unroll
        for (int j = 0; j < 8; j++) {
            int k = kc*32 + q*8 + j;
            float x = (col < 384) ? W_off[(size_t)k*384 + col] : W_attn[(size_t)k*192 + (col-384)];
            v[j] = (bf16)x;
        }
        *reinterpret_cast<bf16x8*>(Woap + (size_t)f2*8) = v;
    } else if (flat < 34816) {
        int f3 = flat - 26624;
        int kc = f3 >> 10, rem = f3 & 1023;
        int nf = rem >> 6, lane = rem & 63;
        int q = lane >> 4, col = nf*16 + (lane & 15);
        bf16x8 v;
        #pragma unroll
        for (int j = 0; j < 8; j++) v[j] = (bf16)W_out[(size_t)(kc*32 + q*8 + j)*256 + col];
        *reinterpret_cast<bf16x8*>(Wop + (size_t)f3*8) = v;
    }
}

// ---------------------------------------------------------------- K2: offsets + attn via MFMA (+softmax)
// 400 blocks x 16 queries. A-frags direct from global (feature rows are k-contiguous).
__global__ __launch_bounds__(256) void k_offattn2(
    const float* __restrict__ feature, const bf16* __restrict__ Woap,
    const float* __restrict__ b_off, const float* __restrict__ b_attn,
    float* __restrict__ offs, bf16* __restrict__ attn_out)
{
    __shared__ float lg[16][200];    // logits [m][192], padded
    int t = threadIdx.x, lane = t & 63, w = t >> 6;
    int q = lane >> 4, r16 = lane & 15;
    int n0 = blockIdx.x * 16;

    f32x4 acc[9];
    #pragma unroll
    for (int i = 0; i < 9; i++) acc[i] = (f32x4){0.f,0.f,0.f,0.f};

    const float* arow = feature + (size_t)(n0 + r16)*CH;
    for (int kc = 0; kc < 8; kc++) {
        f32x4 a0 = *reinterpret_cast<const f32x4*>(arow + kc*32 + q*8);
        f32x4 a1 = *reinterpret_cast<const f32x4*>(arow + kc*32 + q*8 + 4);
        bf16x8 afr;
        #pragma unroll
        for (int i = 0; i < 4; i++) { afr[i] = (bf16)a0[i]; afr[4+i] = (bf16)a1[i]; }
        #pragma unroll
        for (int nf9 = 0; nf9 < 9; nf9++) {
            bf16x8 bfr = *reinterpret_cast<const bf16x8*>(Woap + ((size_t)(kc*36 + w*9 + nf9)*64 + lane)*8);
            acc[nf9] = __builtin_amdgcn_mfma_f32_16x16x32_bf16(afr, bfr, acc[nf9], 0, 0, 0);
        }
    }
    #pragma unroll
    for (int nf9 = 0; nf9 < 9; nf9++) {
        int nfg = w*9 + nf9;
        int nglob = nfg*16 + r16;
        if (nfg < 24) {                       // offsets (wave-uniform branch)
            float bias = b_off[nglob];
            #pragma unroll
            for (int r = 0; r < 4; r++)
                offs[(size_t)(n0 + q*4 + r)*384 + nglob] = acc[nf9][r] + bias;
        } else {                              // attn logits -> LDS
            int la = nglob - 384;
            float bias = b_attn[la];
            #pragma unroll
            for (int r = 0; r < 4; r++)
                lg[q*4 + r][la] = acc[nf9][r] + bias;
        }
    }
    __syncthreads();
    if (t < 128) {
        int m = t >> 3, h = t & 7;
        const float* L = &lg[m][h*24];
        float mx = -1e30f;
        #pragma unroll
        for (int j = 0; j < 24; j++) mx = fmaxf(mx, L[j]);
        float e[24]; float s = 0.f;
        #pragma unroll
        for (int j = 0; j < 24; j++) { e[j] = __expf(L[j] - mx); s += e[j]; }
        float inv = 1.f / s;
        #pragma unroll
        for (int j = 0; j < 24; j++) attn_out[(size_t)(n0+m)*192 + h*24 + j] = (bf16)(e[j]*inv);
    }
}

// ---------------------------------------------------------------- K3: value projection GEMM (MFMA bf16)
// value layout: [cam][head][pos][32ch]  (bf16)
__global__ __launch_bounds__(256) void k_valproj(
    const float* __restrict__ f0, const float* __restrict__ f1, const float* __restrict__ f2,
    const float* __restrict__ cams_embeds, const float* __restrict__ level_embeds,
    const bf16* __restrict__ Wvp, const float* __restrict__ b_val, bf16* __restrict__ value)
{
    __shared__ alignas(16) bf16 A[64][48];    // [m][k], padded row 48 (6144 B)
    __shared__ alignas(16) bf16 Cst[16][256]; // epilogue staging stripe (8192 B)
    int bi = blockIdx.x;
    int cam = bi / 231, mb = bi % 231;
    int lvl, local0, HW;
    const float* fp;
    if (mb < 176)      { lvl = 0; local0 = mb*64;        fp = f0; HW = 11264; }
    else if (mb < 220) { lvl = 1; local0 = (mb-176)*64;  fp = f1; HW = 2816;  }
    else               { lvl = 2; local0 = (mb-220)*64;  fp = f2; HW = 704;   }
    int pos0 = (lvl == 0 ? 0 : (lvl == 1 ? 11264 : 14080)) + local0;
    const float* featbase = fp + (size_t)cam*CH*HW + local0;

    int t = threadIdx.x;
    int lane = t & 63, w = t >> 6;
    int kk = t >> 3;            // 0..31 (channel within chunk)
    int m8 = (t & 7) * 8;       // m start
    int q = lane >> 4, r16 = lane & 15;

    f32x4 acc[4][4];
    #pragma unroll
    for (int i = 0; i < 4; i++)
        #pragma unroll
        for (int j = 0; j < 4; j++) acc[i][j] = (f32x4){0.f,0.f,0.f,0.f};

    for (int kc = 0; kc < 8; kc++) {
        __syncthreads();
        int kg = kc*32 + kk;
        float e = cams_embeds[cam*CH + kg] + level_embeds[lvl*CH + kg];
        f32x4 v0 = *reinterpret_cast<const f32x4*>(featbase + (size_t)kg*HW + m8);
        f32x4 v1 = *reinterpret_cast<const f32x4*>(featbase + (size_t)kg*HW + m8 + 4);
        #pragma unroll
        for (int i = 0; i < 4; i++) A[m8+i][kk]   = (bf16)(v0[i] + e);
        #pragma unroll
        for (int i = 0; i < 4; i++) A[m8+4+i][kk] = (bf16)(v1[i] + e);
        __syncthreads();

        bf16x8 bfr[4];
        #pragma unroll
        for (int nf = 0; nf < 4; nf++) {
            int nfg = w*4 + nf;
            bfr[nf] = *reinterpret_cast<const bf16x8*>(Wvp + ((size_t)(kc*16 + nfg)*64 + lane)*8);
        }
        #pragma unroll
        for (int mf = 0; mf < 4; mf++) {
            bf16x8 afr = *reinterpret_cast<const bf16x8*>(&A[mf*16 + r16][q*8]);
            #pragma unroll
            for (int nf = 0; nf < 4; nf++)
                acc[mf][nf] = __builtin_amdgcn_mfma_f32_16x16x32_bf16(afr, bfr[nf], acc[mf][nf], 0, 0, 0);
        }
    }
    // epilogue, per 16-row stripe -> LDS -> coalesced 16B stores
    int orow = t >> 4;                // 0..15
    int ocol = (t & 15) * 16;         // 0..240 step 16
    int ohead = ocol >> 5, och = ocol & 31;
    #pragma unroll
    for (int mf = 0; mf < 4; mf++) {
        __syncthreads();
        #pragma unroll
        for (int nf = 0; nf < 4; nf++) {
            int c = w*64 + nf*16 + r16;
            float bv = b_val[c];
            #pragma unroll
            for (int r = 0; r < 4; r++)
                Cst[q*4 + r][c] = (bf16)(acc[mf][nf][r] + bv);
        }
        __syncthreads();
        int srow = pos0 + mf*16 + orow;
        bf16* dst = value + ((size_t)(cam*NH + ohead)*S_TOT + srow)*32 + och;
        const f32x4* src = reinterpret_cast<const f32x4*>(&Cst[orow][ocol]);
        f32x4 x0 = src[0], x1 = src[1];
        reinterpret_cast<f32x4*>(dst)[0] = x0;
        reinterpret_cast<f32x4*>(dst)[1] = x1;
    }
}

// ---------------------------------------------------------------- K4: MSDA gather (unchanged from R8)
__global__ __launch_bounds__(256) void k_msda(
    const float* __restrict__ coor, const float* __restrict__ offs,
    const bf16* __restrict__ attn, const bf16* __restrict__ value,
    const float* __restrict__ maskf, float* __restrict__ slots)
{
#if MSDA_DOT2
    __shared__ uint2 s_w[4][48];
#else
    __shared__ f32x4 s_w[4][48];
#endif
    __shared__ int4  s_o[4][48];
    int wv = threadIdx.x >> 6;
    int lane = threadIdx.x & 63;
    int n = blockIdx.x;
    int h0 = wv * 2;
    int p = lane >> 3, k = lane & 7;
    int kb = k * 8;

    float oxr = 0.f, oyr = 0.f, awr = 0.f;
    int smm = h0*24 + lane;
    if (lane < 48) {
        float2 o2 = *reinterpret_cast<const float2*>(offs + (size_t)n*384 + smm*2);
        oxr = o2.x; oyr = o2.y;
        awr = (float)attn[(size_t)n*192 + smm];
    }

    f32x4 acc[2];
    acc[0] = (f32x4){0.f, 0.f, 0.f, 0.f};
    acc[1] = (f32x4){0.f, 0.f, 0.f, 0.f};

    const char* vbyte = (const char*)value;

    for (int cam = 0; cam < NCAMS; cam++) {
        if (maskf[cam*NQ + n] == 0.f) continue;
        float cx = coor[(cam*NQ + n)*2 + 0];
        float cy = coor[(cam*NQ + n)*2 + 1];

        if (lane < 48) {
            int hl = lane / 24;
            int r = lane - hl*24;
            int lvl = r >> 3;
            int h = h0 + hl;
            int wi   = (lvl == 0) ? 176 : ((lvl == 1) ? 88 : 44);
            int hi   = (lvl == 0) ? 64  : ((lvl == 1) ? 32 : 16);
            int base = (lvl == 0) ? 0   : ((lvl == 1) ? 11264 : 14080);
            float x = cx*(float)wi + oxr - 0.5f;
            float y = cy*(float)hi + oyr - 0.5f;
            float xf = floorf(x), yf = floorf(y);
            float tx = x - xf, ty = y - yf;
            float wm1x = (float)(wi-1), wm1y = (float)(hi-1);
            bool vx0 = (xf >= 0.f)      && (xf <= wm1x);
            bool vx1 = (xf+1.f >= 0.f)  && (xf+1.f <= wm1x);
            bool vy0 = (yf >= 0.f)      && (yf <= wm1y);
            bool vy1 = (yf+1.f >= 0.f)  && (yf+1.f <= wm1y);
            int x0 = (int)fminf(fmaxf(xf,      0.f), wm1x);
            int x1 = (int)fminf(fmaxf(xf+1.f,  0.f), wm1x);
            int y0 = (int)fminf(fmaxf(yf,      0.f), wm1y);
            int y1 = (int)fminf(fmaxf(yf+1.f,  0.f), wm1y);
            float w00 = (1.f-tx)*(1.f-ty)*awr * ((vx0 && vy0) ? 1.f : 0.f);
            float w10 = tx*(1.f-ty)*awr       * ((vx1 && vy0) ? 1.f : 0.f);
            float w01 = (1.f-tx)*ty*awr       * ((vx0 && vy1) ? 1.f : 0.f);
            float w11 = tx*ty*awr             * ((vx1 && vy1) ? 1.f : 0.f);
            int rowb = (cam*NH + h)*S_TOT + base;
            int r0 = rowb + y0*wi, r1 = rowb + y1*wi;
#if MSDA_DOT2
            bf16x2 wa; wa[0] = (bf16)w00; wa[1] = (bf16)w10;
            bf16x2 wb; wb[0] = (bf16)w01; wb[1] = (bf16)w11;
            s_w[wv][lane] = make_uint2(__builtin_bit_cast(unsigned, wa),
                                       __builtin_bit_cast(unsigned, wb));
#else
            s_w[wv][lane] = (f32x4){w00, w10, w01, w11};
#endif
            s_o[wv][lane] = make_int4((r0 + x0)*64, (r0 + x1)*64, (r1 + x0)*64, (r1 + x1)*64);
        }

        #pragma unroll
        for (int hl = 0; hl < 2; hl++) {
            #pragma unroll
            for (int lvl = 0; lvl < 3; lvl++) {
                int mml = hl*24 + lvl*8 + p;
                int4  o4 = s_o[wv][mml];
#if MSDA_DOT2
                uint2 wp = s_w[wv][mml];
                bf16x2 wa = __builtin_bit_cast(bf16x2, wp.x);
                bf16x2 wb = __builtin_bit_cast(bf16x2, wp.y);
                uint2 d00 = *reinterpret_cast<const uint2*>(vbyte + (o4.x + kb));
                uint2 d10 = *reinterpret_cast<const uint2*>(vbyte + (o4.y + kb));
                uint2 d01 = *reinterpret_cast<const uint2*>(vbyte + (o4.z + kb));
                uint2 d11 = *reinterpret_cast<const uint2*>(vbyte + (o4.w + kb));
                unsigned a0p = __builtin_amdgcn_perm(d10.x, d00.x, 0x05040100u);
                unsigned a1p = __builtin_amdgcn_perm(d10.x, d00.x, 0x07060302u);
                unsigned a2p = __builtin_amdgcn_perm(d10.y, d00.y, 0x05040100u);
                unsigned a3p = __builtin_amdgcn_perm(d10.y, d00.y, 0x07060302u);
                unsigned b0p = __builtin_amdgcn_perm(d11.x, d01.x, 0x05040100u);
                unsigned b1p = __builtin_amdgcn_perm(d11.x, d01.x, 0x07060302u);
                unsigned b2p = __builtin_amdgcn_perm(d11.y, d01.y, 0x05040100u);
                unsigned b3p = __builtin_amdgcn_perm(d11.y, d01.y, 0x07060302u);
                acc[hl][0] = __builtin_amdgcn_fdot2_f32_bf16(__builtin_bit_cast(bf16x2, a0p), wa, acc[hl][0], false);
                acc[hl][1] = __builtin_amdgcn_fdot2_f32_bf16(__builtin_bit_cast(bf16x2, a1p), wa, acc[hl][1], false);
                acc[hl][2] = __builtin_amdgcn_fdot2_f32_bf16(__builtin_bit_cast(bf16x2, a2p), wa, acc[hl][2], false);
                acc[hl][3] = __builtin_amdgcn_fdot2_f32_bf16(__builtin_bit_cast(bf16x2, a3p), wa, acc[hl][3], false);
                acc[hl][0] = __builtin_amdgcn_fdot2_f32_bf16(__builtin_bit_cast(bf16x2, b0p), wb, acc[hl][0], false);
                acc[hl][1] = __builtin_amdgcn_fdot2_f32_bf16(__builtin_bit_cast(bf16x2, b1p), wb, acc[hl][1], false);
                acc[hl][2] = __builtin_amdgcn_fdot2_f32_bf16(__builtin_bit_cast(bf16x2, b2p), wb, acc[hl][2], false);
                acc[hl][3] = __builtin_amdgcn_fdot2_f32_bf16(__builtin_bit_cast(bf16x2, b3p), wb, acc[hl][3], false);
#else
                f32x4 w4 = s_w[wv][mml];
                uint2 d00 = *reinterpret_cast<const uint2*>(vbyte + (o4.x + kb));
                uint2 d10 = *reinterpret_cast<const uint2*>(vbyte + (o4.y + kb));
                uint2 d01 = *reinterpret_cast<const uint2*>(vbyte + (o4.z + kb));
                uint2 d11 = *reinterpret_cast<const uint2*>(vbyte + (o4.w + kb));
                acc[hl][0] = fmaf(__uint_as_float(d00.x << 16),          w4.x, acc[hl][0]);
                acc[hl][1] = fmaf(__uint_as_float(d00.x & 0xffff0000u),  w4.x, acc[hl][1]);
                acc[hl][2] = fmaf(__uint_as_float(d00.y << 16),          w4.x, acc[hl][2]);
                acc[hl][3] = fmaf(__uint_as_float(d00.y & 0xffff0000u),  w4.x, acc[hl][3]);
                acc[hl][0] = fmaf(__uint_as_float(d10.x << 16),          w4.y, acc[hl][0]);
                acc[hl][1] = fmaf(__uint_as_float(d10.x & 0xffff0000u),  w4.y, acc[hl][1]);
                acc[hl][2] = fmaf(__uint_as_float(d10.y << 16),          w4.y, acc[hl][2]);
                acc[hl][3] = fmaf(__uint_as_float(d10.y & 0xffff0000u),  w4.y, acc[hl][3]);
                acc[hl][0] = fmaf(__uint_as_float(d01.x << 16),          w4.z, acc[hl][0]);
                acc[hl][1] = fmaf(__uint_as_float(d01.x & 0xffff0000u),  w4.z, acc[hl][1]);
                acc[hl][2] = fmaf(__uint_as_float(d01.y << 16),          w4.z, acc[hl][2]);
                acc[hl][3] = fmaf(__uint_as_float(d01.y & 0xffff0000u),  w4.z, acc[hl][3]);
                acc[hl][0] = fmaf(__uint_as_float(d11.x << 16),          w4.w, acc[hl][0]);
                acc[hl][1] = fmaf(__uint_as_float(d11.x & 0xffff0000u),  w4.w, acc[hl][1]);
                acc[hl][2] = fmaf(__uint_as_float(d11.y << 16),          w4.w, acc[hl][2]);
                acc[hl][3] = fmaf(__uint_as_float(d11.y & 0xffff0000u),  w4.w, acc[hl][3]);
#endif
            }
        }
    }

    #pragma unroll
    for (int hl = 0; hl < 2; hl++)
        #pragma unroll
        for (int i = 0; i < 4; i++) {
            acc[hl][i] += __shfl_xor(acc[hl][i], 8);
            acc[hl][i] += __shfl_xor(acc[hl][i], 16);
            acc[hl][i] += __shfl_xor(acc[hl][i], 32);
        }
    if (p == 0) {
        #pragma unroll
        for (int hl = 0; hl < 2; hl++)
            *reinterpret_cast<f32x4*>(slots + (size_t)n*CH + (h0+hl)*32 + k*4) = acc[hl];
    }
}

// ---------------------------------------------------------------- K6: mask-mean + out proj (MFMA) + residual + LN
// 400 blocks x 16 queries; mask-mean folded into A-frag scale; fused LN.
__global__ __launch_bounds__(256) void k_final2(
    const float* __restrict__ slots, const float* __restrict__ maskf,
    const bf16* __restrict__ Wop, const float* __restrict__ b_out,
    const float* __restrict__ feature, const float* __restrict__ ln_g,
    const float* __restrict__ ln_b, float* __restrict__ out)
{
    __shared__ float yb[16][264];    // y rows, padded (264) for conflict-free scattered writes
    int t = threadIdx.x, lane = t & 63, w = t >> 6;
    int q = lane >> 4, r16 = lane & 15;
    int n0 = blockIdx.x * 16;

    float msum = 0.f;
    #pragma unroll
    for (int cam = 0; cam < NCAMS; cam++) msum += maskf[cam*NQ + n0 + r16];
    float inv = 1.f / fmaxf(msum, 1.f);

    f32x4 acc[4];
    #pragma unroll
    for (int i = 0; i < 4; i++) acc[i] = (f32x4){0.f,0.f,0.f,0.f};

    const float* srow = slots + (size_t)(n0 + r16)*CH;
    for (int kc = 0; kc < 8; kc++) {
        f32x4 a0 = *reinterpret_cast<const f32x4*>(srow + kc*32 + q*8);
        f32x4 a1 = *reinterpret_cast<const f32x4*>(srow + kc*32 + q*8 + 4);
        bf16x8 afr;
        #pragma unroll
        for (int i = 0; i < 4; i++) { afr[i] = (bf16)(a0[i]*inv); afr[4+i] = (bf16)(a1[i]*inv); }
        #pragma unroll
        for (int nf = 0; nf < 4; nf++) {
            bf16x8 bfr = *reinterpret_cast<const bf16x8*>(Wop + ((size_t)(kc*16 + w*4 + nf)*64 + lane)*8);
            acc[nf] = __builtin_amdgcn_mfma_f32_16x16x32_bf16(afr, bfr, acc[nf], 0, 0, 0);
        }
    }
    #pragma unroll
    for (int nf = 0; nf < 4; nf++) {
        int c = (w*4 + nf)*16 + r16;
        float bias = b_out[c];
        #pragma unroll
        for (int r = 0; r < 4; r++) {
            int m = q*4 + r;
            yb[m][c] = acc[nf][r] + bias + feature[(size_t)(n0+m)*CH + c];
        }
    }
    __syncthreads();
    // LN: row = t>>4 (16 rows), l16 = t&15 each sums 16 elements
    int row = t >> 4, l16 = t & 15;
    int c0 = l16 * 16;
    float s = 0.f, s2 = 0.f;
    #pragma unroll
    for (int j = 0; j < 16; j++) {
        float v = yb[row][c0 + j];
        s += v; s2 += v*v;
    }
    #pragma unroll
    for (int off = 1; off < 16; off <<= 1) {
        s  += __shfl_xor(s, off);
        s2 += __shfl_xor(s2, off);
    }
    float mu = s / 256.f;
    float rsig = rsqrtf(s2 / 256.f - mu*mu + 1e-5f);
    float* orow = out + (size_t)(n0 + row)*CH + c0;
    #pragma unroll
    for (int j4 = 0; j4 < 4; j4++) {
        f32x4 o;
        #pragma unroll
        for (int i = 0; i < 4; i++) {
            int c = c0 + j4*4 + i;
            o[i] = (yb[row][c] - mu) * rsig * ln_g[c] + ln_b[c];
        }
        *reinterpret_cast<f32x4*>(orow + j4*4) = o;
    }
}

// ---------------------------------------------------------------- launch
extern "C" void kernel_launch(void* const* d_in, const int* in_sizes, int n_in,
                              void* d_out, int out_size, void* d_ws, size_t ws_size,
                              hipStream_t stream)
{
    const float* means       = (const float*)d_in[0];
    const float* feature     = (const float*)d_in[1];
    const float* feat0       = (const float*)d_in[2];
    const float* feat1       = (const float*)d_in[3];
    const float* feat2       = (const float*)d_in[4];
    const float* cam2ego     = (const float*)d_in[5];
    const float* intrins     = (const float*)d_in[6];
    const float* post_rots   = (const float*)d_in[7];
    const float* post_trans  = (const float*)d_in[8];
    const float* W_off       = (const float*)d_in[9];
    const float* b_off       = (const float*)d_in[10];
    const float* W_attn      = (const float*)d_in[11];
    const float* b_attn      = (const float*)d_in[12];
    const float* W_val       = (const float*)d_in[13];
    const float* b_val       = (const float*)d_in[14];
    const float* W_out       = (const float*)d_in[15];
    const float* b_out       = (const float*)d_in[16];
    const float* cams_embeds = (const float*)d_in[17];
    const float* level_embeds= (const float*)d_in[18];
    const float* ln_g        = (const float*)d_in[19];
    const float* ln_b        = (const float*)d_in[20];
    const int*   img_h       = (const int*)d_in[21];
    const int*   img_w       = (const int*)d_in[22];

    // workspace layout (total 65,275,904 B = 62.3 MiB)
    char* ws = (char*)d_ws;
    float* coor  = (float*)(ws + 0);           //  6*6400*2 f32      =   307,200
    float* maskf = (float*)(ws + 307200);      //  6*6400 f32        =   153,600
    float* offs  = (float*)(ws + 460800);      //  6400*384 f32      = 9,830,400
    bf16*  attn  = (bf16*) (ws + 10291200);    //  6400*192 bf16     = 2,457,600
    bf16*  Wvp   = (bf16*) (ws + 12748800);    //  256*256 bf16      =   131,072
    bf16*  Woap  = (bf16*) (ws + 12879872);    //  256*576 bf16      =   294,912
    bf16*  Wop   = (bf16*) (ws + 13174784);    //  256*256 bf16      =   131,072
    float* slots = (float*)(ws + 13305856);    //  6400*256 f32      = 6,553,600
    bf16*  value = (bf16*) (ws + 19859456);    //  6*8*14784*32 bf16 = 45,416,448
    if (ws_size < 65275904u) return;

    k_prep    <<<286, 256, 0, stream>>>(means, cam2ego, intrins, post_rots, post_trans,
                                        img_h, img_w, W_val, W_off, W_attn, W_out,
                                        coor, maskf, Wvp, Woap, Wop);
    k_offattn2<<<400, 256, 0, stream>>>(feature, Woap, b_off, b_attn, offs, attn);
    k_valproj <<<1386, 256, 0, stream>>>(feat0, feat1, feat2, cams_embeds, level_embeds, Wvp, b_val, value);
    k_msda    <<<6400, 256, 0, stream>>>(coor, offs, attn, value, maskf, slots);
    k_final2  <<<400, 256, 0, stream>>>(slots, maskf, Wop, b_out, feature, ln_g, ln_b, (float*)d_out);
}